// Round 21
// baseline (425.684 us; speedup 1.0000x reference)
//
#include <hip/hip_runtime.h>
#include <math.h>

#define BB 4
#define LL 1024
#define DIN 64
#define DD 512
#define HH 8
#define DH 64
#define NLAYER 3
#define DFF 2048
#define FEAT 530
#define FEATP 576
#define MM 4096

typedef float f32x4 __attribute__((ext_vector_type(4)));
typedef short s16x8 __attribute__((ext_vector_type(8)));

__device__ __forceinline__ unsigned short f2bf(float f) {
    unsigned int u = __float_as_uint(f);
    u += 0x7fffu + ((u >> 16) & 1u);
    return (unsigned short)(u >> 16);
}
__device__ __forceinline__ float bf2f(unsigned short u) {
    return __uint_as_float(((unsigned int)u) << 16);
}
__device__ __forceinline__ float gelu_exact(float x) {
    return 0.5f * x * (1.0f + erff(x * 0.7071067811865475f));
}
__device__ __forceinline__ float wave_reduce_sum(float v) {
    #pragma unroll
    for (int o = 32; o; o >>= 1) v += __shfl_down(v, o);
    return v;
}
__device__ __forceinline__ void gload16(const unsigned short* g, unsigned short* l) {
    __builtin_amdgcn_global_load_lds(
        (const __attribute__((address_space(1))) unsigned int*)g,
        (__attribute__((address_space(3))) unsigned int*)l, 16, 0, 0);
}
__device__ __forceinline__ void cvt16(const float* src, unsigned short* dst) {
    float4 f0 = ((const float4*)src)[0];
    float4 f1 = ((const float4*)src)[1];
    float4 f2 = ((const float4*)src)[2];
    float4 f3 = ((const float4*)src)[3];
    ushort4 o0, o1, o2, o3;
    o0.x = f2bf(f0.x); o0.y = f2bf(f0.y); o0.z = f2bf(f0.z); o0.w = f2bf(f0.w);
    o1.x = f2bf(f1.x); o1.y = f2bf(f1.y); o1.z = f2bf(f1.z); o1.w = f2bf(f1.w);
    o2.x = f2bf(f2.x); o2.y = f2bf(f2.y); o2.z = f2bf(f2.z); o2.w = f2bf(f2.w);
    o3.x = f2bf(f3.x); o3.y = f2bf(f3.y); o3.z = f2bf(f3.z); o3.w = f2bf(f3.w);
    ((ushort4*)dst)[0] = o0;
    ((ushort4*)dst)[1] = o1;
    ((ushort4*)dst)[2] = o2;
    ((ushort4*)dst)[3] = o3;
}

// ------------- small prologue: PE/z (1024) | small converts (256) | delay (4) -------------
__global__ __launch_bounds__(256) void prologue_kernel(
    const float* __restrict__ c_local, const float* __restrict__ c_sink,
    const int* __restrict__ lengths,
    const float* __restrict__ beta_p, const float* __restrict__ floor_p,
    const float* __restrict__ gamma_p,
    unsigned short* __restrict__ Z, float* __restrict__ srow,
    const float* __restrict__ x, const float* __restrict__ in_w,
    const float* __restrict__ cpe_w,
    unsigned short* __restrict__ x_bf, unsigned short* __restrict__ w_in,
    unsigned short* __restrict__ w_cpe,
    const float* __restrict__ delay, const float* __restrict__ de_w1, const float* __restrict__ de_b1,
    const float* __restrict__ de_w2, const float* __restrict__ de_b2,
    const float* __restrict__ de_lng, const float* __restrict__ de_lnb,
    float* __restrict__ e)
{
    int blk = blockIdx.x;
    int t = threadIdx.x;

    if (blk < LL) {
        // ---- PE row l (shared by all 4 batches) + per-(b,l) tails ----
        int l = blk;
        for (int d = t; d < DD; d += 256) {
            int i = d >> 1;
            float dv = expf((float)(2 * i) * (-0.017988946135618352f)); // -ln(1e4)/512
            float ang = (float)l * dv;
            unsigned short pv = f2bf((d & 1) ? cosf(ang) : sinf(ang));
            #pragma unroll
            for (int bb = 0; bb < 4; ++bb)
                Z[(size_t)(bb * LL + l) * FEATP + d] = pv;
        }
        {
            int bb = t >> 6, j = t & 63;
            float cl = c_local[(size_t)bb * LL + l]; cl = fminf(fmaxf(cl, 0.f), 1.f);
            float cs = c_sink [(size_t)bb * LL + l]; cs = fminf(fmaxf(cs, 0.f), 1.f);
            float v = 0.f;
            if (j == 0) v = cl;
            else if (j == 1) v = cs;
            else if (j < 10)  { float c = (float)(j - 2) * (1.0f / 7.0f);  float df = (cl - c) / 0.200001f; v = expf(-0.5f * df * df); }
            else if (j < 18)  { float c = (float)(j - 10) * (1.0f / 7.0f); float df = (cs - c) / 0.200001f; v = expf(-0.5f * df * df); }
            Z[(size_t)(bb * LL + l) * FEATP + 512 + j] = (j < 18) ? f2bf(v) : 0;
            if (j == 32) {
                float sv = (*beta_p) * ((*floor_p) + (1.f - (*floor_p)) * powf(cs + 1e-6f, *gamma_p));
                srow[bb * LL + l] = (l < lengths[bb]) ? sv : 0.f;
            }
        }
    } else if (blk < LL + 256) {
        // ---- small converts: x, in_w, cpe pad ----
        const int N0s = MM * DIN;            // 262144
        const int N1s = N0s + 512 * 64;      // +32768
        const int NCHs = N1s / 16;
        int vb = blk - LL;
        for (int c = vb * 256 + t; c < NCHs; c += 256 * 256) {
            int i = c * 16;
            if (i < N0s) cvt16(x + i, x_bf + i);
            else         cvt16(in_w + (i - N0s), w_in + (i - N0s));
        }
        for (int j = vb * 256 + t; j < 512 * FEATP; j += 256 * 256) {
            int r = j / FEATP, c2 = j - r * FEATP;
            w_cpe[j] = (c2 < FEAT) ? f2bf(cpe_w[(size_t)r * FEAT + c2]) : 0;
        }
    } else {
        // ---- delay encoder, 256 threads (each owns rows t and t+256) ----
        __shared__ float g1[DD];
        __shared__ float red[16];
        int b = blk - (LL + 256);
        float d0 = delay[b];
        g1[t]       = gelu_exact(d0 * de_w1[t]       + de_b1[t]);
        g1[t + 256] = gelu_exact(d0 * de_w1[t + 256] + de_b1[t + 256]);
        __syncthreads();
        float s0 = de_b2[t], s1 = de_b2[t + 256];
        const float* wr0 = de_w2 + (size_t)t * DD;
        const float* wr1 = de_w2 + (size_t)(t + 256) * DD;
        for (int j = 0; j < DD; j += 4) {
            float4 a4 = *(const float4*)(wr0 + j);
            float4 b4 = *(const float4*)(wr1 + j);
            float gj0 = g1[j], gj1 = g1[j+1], gj2 = g1[j+2], gj3 = g1[j+3];
            s0 += a4.x * gj0 + a4.y * gj1 + a4.z * gj2 + a4.w * gj3;
            s1 += b4.x * gj0 + b4.y * gj1 + b4.z * gj2 + b4.w * gj3;
        }
        float s = s0 + s1, ss = s0 * s0 + s1 * s1;
        float rs = wave_reduce_sum(s), rss = wave_reduce_sum(ss);
        int lane = t & 63, w = t >> 6;
        if (lane == 0) { red[w] = rs; red[8 + w] = rss; }
        __syncthreads();
        float mean = 0.f, msq = 0.f;
        #pragma unroll
        for (int i = 0; i < 4; ++i) { mean += red[i]; msq += red[8 + i]; }
        mean *= (1.0f / DD); msq *= (1.0f / DD);
        float rstd = rsqrtf(msq - mean * mean + 1e-5f);
        e[(size_t)b * DD + t]       = (s0 - mean) * rstd * de_lng[t]       + de_lnb[t];
        e[(size_t)b * DD + t + 256] = (s1 - mean) * rstd * de_lng[t + 256] + de_lnb[t + 256];
    }
}

// ---- GEMM body (BK=64, dbuf LDS, runtime mode), shared by gemm_t and dual kernels ----
template<int BM, int BN, int FM, int FN, int WGN>
__device__ __forceinline__ void gemm_body(
    const unsigned short* __restrict__ A, const unsigned short* __restrict__ W,
    const float* __restrict__ bias, const float* __restrict__ resid,
    float* __restrict__ outf, unsigned short* __restrict__ outb,
    int M, int N, int K, int mode, int bm, int bn,
    unsigned short* As, unsigned short* Ws)
{
    int t = threadIdx.x;
    int lane = t & 63, wid = t >> 6;
    int wr = wid / WGN, wc = wid % WGN;
    int l15 = lane & 15, lg = lane >> 4;
    int sr = lane >> 3;
    int sc = ((lane & 7) ^ sr) * 8;
    int ph0 = (lg ^ (l15 & 7)) * 8;
    int ph1 = ((lg + 4) ^ (l15 & 7)) * 8;

    f32x4 acc[FM][FN] = {};
    int nk = K >> 6;

    auto stage = [&](int buf, int ks) {
        int kb = ks * 64;
        #pragma unroll
        for (int i = 0; i < BM / 32; ++i) {
            int row = wid * (BM / 4) + i * 8 + sr;
            gload16(A + (size_t)(bm + row) * K + kb + sc, &As[(size_t)buf * BM * 64 + (wid * (BM / 4) + i * 8) * 64]);
        }
        #pragma unroll
        for (int i = 0; i < BN / 32; ++i) {
            int row = wid * (BN / 4) + i * 8 + sr;
            gload16(W + (size_t)(bn + row) * K + kb + sc, &Ws[(size_t)buf * BN * 64 + (wid * (BN / 4) + i * 8) * 64]);
        }
    };

    stage(0, 0);
    __syncthreads();

    int cur = 0;
    for (int ks = 0; ks < nk; ++ks) {
        if (ks + 1 < nk) stage(cur ^ 1, ks + 1);
        s16x8 af0[FM], af1[FM], wf0[FN], wf1[FN];
        #pragma unroll
        for (int mi = 0; mi < FM; ++mi) {
            int row = wr * FM * 16 + mi * 16 + l15;
            af0[mi] = *(const s16x8*)&As[(size_t)cur * BM * 64 + row * 64 + ph0];
            af1[mi] = *(const s16x8*)&As[(size_t)cur * BM * 64 + row * 64 + ph1];
        }
        #pragma unroll
        for (int ni = 0; ni < FN; ++ni) {
            int row = wc * FN * 16 + ni * 16 + l15;
            wf0[ni] = *(const s16x8*)&Ws[(size_t)cur * BN * 64 + row * 64 + ph0];
            wf1[ni] = *(const s16x8*)&Ws[(size_t)cur * BN * 64 + row * 64 + ph1];
        }
        #pragma unroll
        for (int mi = 0; mi < FM; ++mi)
            #pragma unroll
            for (int ni = 0; ni < FN; ++ni) {
                acc[mi][ni] = __builtin_amdgcn_mfma_f32_16x16x32_bf16(af0[mi], wf0[ni], acc[mi][ni], 0, 0, 0);
                acc[mi][ni] = __builtin_amdgcn_mfma_f32_16x16x32_bf16(af1[mi], wf1[ni], acc[mi][ni], 0, 0, 0);
            }
        __syncthreads();
        cur ^= 1;
    }

    int rbase = (lane >> 4) * 4;
    #pragma unroll
    for (int mi = 0; mi < FM; ++mi) {
        #pragma unroll
        for (int ni = 0; ni < FN; ++ni) {
            int n = bn + wc * FN * 16 + ni * 16 + l15;
            float bzc = (mode == 4) ? 0.f : bias[n];
            #pragma unroll
            for (int r2 = 0; r2 < 4; ++r2) {
                int m = bm + wr * FM * 16 + mi * 16 + rbase + r2;
                float v = acc[mi][ni][r2] + ((mode == 4) ? bias[m] : bzc);
                size_t o = (size_t)m * N + n;
                if (mode == 0)      outf[o] = v;
                else if (mode == 1) outb[o] = f2bf(v);
                else if (mode == 2) outf[o] = v + resid[o];
                else if (mode == 3) outb[o] = f2bf(gelu_exact(v));
                else                outb[o] = f2bf(v);
            }
        }
    }
}

// ---- standalone templated GEMM ----
template<int BM, int BN, int FM, int FN, int WGN, int MODE>
__global__ __launch_bounds__(256) void gemm_t(
    const unsigned short* __restrict__ A, const unsigned short* __restrict__ W,
    const float* __restrict__ bias, const float* __restrict__ resid,
    float* __restrict__ outf, unsigned short* __restrict__ outb,
    int M, int N, int K)
{
    __shared__ __align__(16) unsigned short As[2 * BM * 64];
    __shared__ __align__(16) unsigned short Ws[2 * BN * 64];
    gemm_body<BM, BN, FM, FN, WGN>(A, W, bias, resid, outf, outb, M, N, K, MODE,
                                   blockIdx.y * BM, blockIdx.x * BN, As, Ws);
}

// ---- dual dispatch: h0 GEMM (512) + cpe GEMM (512) + big-weight converts (1024) ----
__global__ __launch_bounds__(256) void gemm_pre_dual(
    const unsigned short* __restrict__ x_bf, const unsigned short* __restrict__ w_in,
    const float* __restrict__ in_b, float* __restrict__ h,
    const unsigned short* __restrict__ Zb, const unsigned short* __restrict__ w_cpe,
    const float* __restrict__ cpe_b, float* __restrict__ cpe_pre,
    const float* __restrict__ inproj_w, const float* __restrict__ outproj_w,
    const float* __restrict__ ff_w1, const float* __restrict__ ff_w2,
    unsigned short* __restrict__ w_inproj, unsigned short* __restrict__ w_outproj,
    unsigned short* __restrict__ w_ff1, unsigned short* __restrict__ w_ff2)
{
    __shared__ __align__(16) unsigned short As[2 * 64 * 64];
    __shared__ __align__(16) unsigned short Ws[2 * 64 * 64];
    int id = blockIdx.x;
    if (id < 512) {
        gemm_body<64, 64, 2, 2, 2>(x_bf, w_in, in_b, nullptr, h, nullptr,
                                   MM, DD, DIN, 0, (id >> 3) * 64, (id & 7) * 64, As, Ws);
    } else if (id < 1024) {
        id -= 512;
        gemm_body<64, 64, 2, 2, 2>(Zb, w_cpe, cpe_b, nullptr, cpe_pre, nullptr,
                                   MM, DD, FEATP, 0, (id >> 3) * 64, (id & 7) * 64, As, Ws);
    } else {
        // big-weight converts: overlap memory pipe with the GEMM blocks' MFMA.
        // These outputs are first read by gemm_qkv_dual (2 dispatches later);
        // the dispatch retires only when all blocks finish -> ordering safe.
        const int B0 = 3 * 1536 * 512;
        const int B1 = B0 + 3 * 512 * 512;
        const int B2 = B1 + 3 * 2048 * 512;
        const int B3 = B2 + 3 * 512 * 2048;
        const int NCH = B3 / 16;
        int vb = id - 1024;
        int t = threadIdx.x;
        for (int c = vb * 256 + t; c < NCH; c += 1024 * 256) {
            int i = c * 16;
            if (i < B0)      cvt16(inproj_w + i,         w_inproj + i);
            else if (i < B1) cvt16(outproj_w + (i - B0), w_outproj + (i - B0));
            else if (i < B2) cvt16(ff_w1 + (i - B1),     w_ff1 + (i - B1));
            else             cvt16(ff_w2 + (i - B2),     w_ff2 + (i - B2));
        }
    }
}

// ---- dual dispatch: QK GEMM (1024 blocks) + V^T GEMM (512 blocks) ----
__global__ __launch_bounds__(256) void gemm_qkv_dual(
    const unsigned short* __restrict__ act1,
    const unsigned short* __restrict__ wqk, const float* __restrict__ qk_bias,
    unsigned short* __restrict__ qkb,
    const unsigned short* __restrict__ wv, const float* __restrict__ v_bias,
    unsigned short* __restrict__ vtb)
{
    __shared__ __align__(16) unsigned short As[2 * 64 * 64];
    __shared__ __align__(16) unsigned short Ws[2 * 64 * 64];
    int id = blockIdx.x;
    if (id < 1024) {
        gemm_body<64, 64, 2, 2, 2>(act1, wqk, qk_bias, nullptr, nullptr, qkb,
                                   MM, 1024, DD, 1, (id >> 4) * 64, (id & 15) * 64, As, Ws);
    } else {
        id -= 1024;
        gemm_body<64, 64, 2, 2, 2>(wv, act1, v_bias, nullptr, nullptr, vtb,
                                   DD, MM, DD, 4, (id >> 6) * 64, (id & 63) * 64, As, Ws);
    }
}

// ------------- MFMA flash attention: natural block order (XCD-balanced), dbuf K/V -------------
#define SK 72
#define SPB 72
__global__ __launch_bounds__(256) void attn_mfma(
    const unsigned short* __restrict__ qk, const unsigned short* __restrict__ Vt,
    const float* __restrict__ c_local, const float* __restrict__ srow,
    const int* __restrict__ lengths,
    const float* __restrict__ alpha_p,
    unsigned short* __restrict__ o)
{
    __shared__ __align__(16) unsigned short Ks[2][64 * SK];
    __shared__ __align__(16) unsigned short Vts[2][64 * SK];
    __shared__ __align__(16) unsigned short Psb[64 * SPB];

    int id = blockIdx.x;
    int q0 = (id & 15) * 64;
    int hh = (id >> 4) & 7;
    int b  = id >> 7;

    int t  = threadIdx.x;
    int lane = t & 63, w = t >> 6;
    int l15 = lane & 15, lg = lane >> 4;
    int len = lengths[b];
    int nt = (len + 63) >> 6;
    int kt0 = q0 >> 6;
    bool sink_blk = (q0 == 0);
    const float alpha = *alpha_p;

    const unsigned short* qrow = qk + (size_t)(b * LL + q0 + w * 16 + l15) * 1024 + hh * DH;
    s16x8 qf0 = *(const s16x8*)(qrow + lg * 8);
    s16x8 qf1 = *(const s16x8*)(qrow + 32 + lg * 8);
    #pragma unroll
    for (int j = 0; j < 8; ++j) {
        qf0[j] = (short)f2bf(bf2f((unsigned short)qf0[j]) * 0.125f);
        qf1[j] = (short)f2bf(bf2f((unsigned short)qf1[j]) * 0.125f);
    }

    float cm1[4], cp1[4];
    #pragma unroll
    for (int r2 = 0; r2 < 4; ++r2) {
        int qi = q0 + w * 16 + lg * 4 + r2;
        cm1[r2] = 0.f; cp1[r2] = 0.f;
        if (qi >= 1 && qi < len) {
            int src = (qi == 1 || qi == LL - 1) ? qi : qi - 1;
            cm1[r2] = alpha * c_local[(size_t)b * LL + src];
        }
        if (qi + 1 < LL && qi < len)
            cp1[r2] = alpha * c_local[(size_t)b * LL + qi + 1];
    }
    bool need_sink = (sink_blk && w == 0 && lg == 0);

    float m_run[4], l_run[4];
    f32x4 accO[4] = {};
    #pragma unroll
    for (int r2 = 0; r2 < 4; ++r2) { m_run[r2] = -1e30f; l_run[r2] = 0.f; }

    int sr = t >> 3, sc8 = (t & 7) * 8;
    const unsigned short* kbase = qk + (size_t)(b * LL) * 1024 + 512 + hh * DH;
    const unsigned short* vbase = Vt + (size_t)(hh * DH) * MM + b * LL;

    uint4 pk0 = *(const uint4*)(kbase + (size_t)sr * 1024 + sc8);
    uint4 pk1 = *(const uint4*)(kbase + (size_t)(sr + 32) * 1024 + sc8);
    uint4 pv0 = *(const uint4*)(vbase + (size_t)sr * MM + sc8);
    uint4 pv1 = *(const uint4*)(vbase + (size_t)(sr + 32) * MM + sc8);
    *(uint4*)&Ks[0][sr * SK + sc8]         = pk0;
    *(uint4*)&Ks[0][(sr + 32) * SK + sc8]  = pk1;
    *(uint4*)&Vts[0][sr * SK + sc8]        = pv0;
    *(uint4*)&Vts[0][(sr + 32) * SK + sc8] = pv1;
    __syncthreads();

    int cur = 0;
    for (int kt = 0; kt < nt; ++kt) {
        int k0 = kt * 64;
        bool pre = (kt + 1 < nt);
        if (pre) {
            int kn = k0 + 64;
            pk0 = *(const uint4*)(kbase + (size_t)(kn + sr) * 1024 + sc8);
            pk1 = *(const uint4*)(kbase + (size_t)(kn + sr + 32) * 1024 + sc8);
            pv0 = *(const uint4*)(vbase + (size_t)sr * MM + kn + sc8);
            pv1 = *(const uint4*)(vbase + (size_t)(sr + 32) * MM + kn + sc8);
        }

        f32x4 accS[4] = {};
        #pragma unroll
        for (int ct = 0; ct < 4; ++ct) {
            s16x8 kf0 = *(const s16x8*)&Ks[cur][(ct * 16 + l15) * SK + lg * 8];
            s16x8 kf1 = *(const s16x8*)&Ks[cur][(ct * 16 + l15) * SK + 32 + lg * 8];
            accS[ct] = __builtin_amdgcn_mfma_f32_16x16x32_bf16(qf0, kf0, accS[ct], 0, 0, 0);
            accS[ct] = __builtin_amdgcn_mfma_f32_16x16x32_bf16(qf1, kf1, accS[ct], 0, 0, 0);
        }

        float m4[4] = { -1e30f, -1e30f, -1e30f, -1e30f };
        bool slow = sink_blk || (kt >= kt0 - 1 && kt <= kt0 + 1) || (k0 + 64 > len);
        if (!slow) {
            #pragma unroll
            for (int ct = 0; ct < 4; ++ct)
                #pragma unroll
                for (int r2 = 0; r2 < 4; ++r2)
                    m4[r2] = fmaxf(m4[r2], accS[ct][r2]);
        } else if (k0 + 64 <= len) {
            #pragma unroll
            for (int ct = 0; ct < 4; ++ct) {
                int k = k0 + ct * 16 + l15;
                float sink_ct = need_sink ? srow[(size_t)b * LL + k] : 0.f;
                #pragma unroll
                for (int r2 = 0; r2 < 4; ++r2) {
                    int qi = q0 + w * 16 + lg * 4 + r2;
                    float v = accS[ct][r2];
                    if (k == qi - 1) v += cm1[r2];
                    else if (k == qi + 1) v += cp1[r2];
                    if (r2 == 0) v += sink_ct;
                    accS[ct][r2] = v;
                    m4[r2] = fmaxf(m4[r2], v);
                }
            }
        } else {
            #pragma unroll
            for (int ct = 0; ct < 4; ++ct) {
                int k = k0 + ct * 16 + l15;
                bool maskk = (k >= len);
                float sink_ct = need_sink ? srow[(size_t)b * LL + k] : 0.f;
                #pragma unroll
                for (int r2 = 0; r2 < 4; ++r2) {
                    int qi = q0 + w * 16 + lg * 4 + r2;
                    float v = accS[ct][r2];
                    if (k == qi - 1) v += cm1[r2];
                    else if (k == qi + 1 && !maskk) v += cp1[r2];
                    if (r2 == 0) v += sink_ct;
                    if (maskk) v -= 10000.f;
                    accS[ct][r2] = v;
                    m4[r2] = fmaxf(m4[r2], v);
                }
            }
        }

        #pragma unroll
        for (int r2 = 0; r2 < 4; ++r2) {
            #pragma unroll
            for (int msk = 1; msk < 16; msk <<= 1) m4[r2] = fmaxf(m4[r2], __shfl_xor(m4[r2], msk));
            float mnew = fmaxf(m_run[r2], m4[r2]);
            float scl = __expf(m_run[r2] - mnew);
            m_run[r2] = mnew;
            float rowsum = 0.f;
            #pragma unroll
            for (int ct = 0; ct < 4; ++ct) {
                float p = __expf(accS[ct][r2] - mnew);
                rowsum += p;
                Psb[(w * 16 + lg * 4 + r2) * SPB + ct * 16 + l15] = f2bf(p);
            }
            #pragma unroll
            for (int msk = 1; msk < 16; msk <<= 1) rowsum += __shfl_xor(rowsum, msk);
            l_run[r2] = l_run[r2] * scl + rowsum;
            #pragma unroll
            for (int dt = 0; dt < 4; ++dt) accO[dt][r2] *= scl;
        }

        #pragma unroll
        for (int kk = 0; kk < 2; ++kk) {
            s16x8 pf = *(const s16x8*)&Psb[(w * 16 + l15) * SPB + kk * 32 + lg * 8];
            #pragma unroll
            for (int dt = 0; dt < 4; ++dt) {
                s16x8 vf = *(const s16x8*)&Vts[cur][(dt * 16 + l15) * SK + kk * 32 + lg * 8];
                accO[dt] = __builtin_amdgcn_mfma_f32_16x16x32_bf16(pf, vf, accO[dt], 0, 0, 0);
            }
        }

        if (pre) {
            int nxt = cur ^ 1;
            *(uint4*)&Ks[nxt][sr * SK + sc8]         = pk0;
            *(uint4*)&Ks[nxt][(sr + 32) * SK + sc8]  = pk1;
            *(uint4*)&Vts[nxt][sr * SK + sc8]        = pv0;
            *(uint4*)&Vts[nxt][(sr + 32) * SK + sc8] = pv1;
        }
        __syncthreads();
        cur ^= 1;
    }

    #pragma unroll
    for (int r2 = 0; r2 < 4; ++r2) {
        float inv = 1.f / l_run[r2];
        int qi = q0 + w * 16 + lg * 4 + r2;
        #pragma unroll
        for (int dt = 0; dt < 4; ++dt)
            o[(size_t)(b * LL + qi) * DD + hh * DH + dt * 16 + l15] = f2bf(accO[dt][r2] * inv);
    }
}

// ------ embed epilogue: h += e + mask?0:gain*LN(cpe_pre) ------
__global__ __launch_bounds__(256) void embed_ep_kernel(
    const float* __restrict__ cpe_pre, const float* __restrict__ e,
    const int* __restrict__ lengths,
    const float* __restrict__ cpe_g, const float* __restrict__ cpe_lb,
    const float* __restrict__ gain_p, float* __restrict__ h)
{
    int row = blockIdx.x;
    int b = row >> 10, l = row & 1023;
    int t = threadIdx.x;
    __shared__ float red[16];
    const float* cp = cpe_pre + (size_t)row * DD;
    float v0 = cp[t], v1 = cp[t + 256];
    float s = v0 + v1, ss = v0 * v0 + v1 * v1;
    float rs = wave_reduce_sum(s), rss = wave_reduce_sum(ss);
    int lane = t & 63, w = t >> 6;
    if (lane == 0) { red[w] = rs; red[8 + w] = rss; }
    __syncthreads();
    float mean = 0.f, msq = 0.f;
    #pragma unroll
    for (int i = 0; i < 4; ++i) { mean += red[i]; msq += red[8 + i]; }
    mean *= (1.0f / DD); msq *= (1.0f / DD);
    float rstd = rsqrtf(msq - mean * mean + 1e-5f);
    bool maskp = (l >= lengths[b]);
    float gain = *gain_p;
    float pe0 = maskp ? 0.f : gain * ((v0 - mean) * rstd * cpe_g[t] + cpe_lb[t]);
    float pe1 = maskp ? 0.f : gain * ((v1 - mean) * rstd * cpe_g[t + 256] + cpe_lb[t + 256]);
    h[(size_t)row * DD + t]       += e[(size_t)b * DD + t] + pe0;
    h[(size_t)row * DD + t + 256] += e[(size_t)b * DD + t + 256] + pe1;
}

// ---------------- LayerNorm f32 out (final) ----------------
__global__ __launch_bounds__(256) void ln_kernel(
    const float* __restrict__ in, float* __restrict__ out,
    const float* __restrict__ g, const float* __restrict__ bta)
{
    int row = blockIdx.x; int t = threadIdx.x;
    __shared__ float red[16];
    const float* xr = in + (size_t)row * DD;
    float2 v = ((const float2*)xr)[t];
    float s = v.x + v.y, ss = v.x * v.x + v.y * v.y;
    float rs = wave_reduce_sum(s), rss = wave_reduce_sum(ss);
    int lane = t & 63, w = t >> 6;
    if (lane == 0) { red[w] = rs; red[8 + w] = rss; }
    __syncthreads();
    float mean = 0.f, msq = 0.f;
    #pragma unroll
    for (int i = 0; i < 4; ++i) { mean += red[i]; msq += red[8 + i]; }
    mean *= (1.0f / DD); msq *= (1.0f / DD);
    float rstd = rsqrtf(msq - mean * mean + 1e-5f);
    float2 gg = ((const float2*)g)[t], bb = ((const float2*)bta)[t];
    float2 o;
    o.x = (v.x - mean) * rstd * gg.x + bb.x;
    o.y = (v.y - mean) * rstd * gg.y + bb.y;
    ((float2*)(out + (size_t)row * DD))[t] = o;
}

// ---------------- LayerNorm bf16 out ----------------
__global__ __launch_bounds__(256) void ln_bf16_kernel(
    const float* __restrict__ in, unsigned short* __restrict__ out,
    const float* __restrict__ g, const float* __restrict__ bta)
{
    int row = blockIdx.x; int t = threadIdx.x;
    __shared__ float red[16];
    const float* xr = in + (size_t)row * DD;
    float2 v = ((const float2*)xr)[t];
    float s = v.x + v.y, ss = v.x * v.x + v.y * v.y;
    float rs = wave_reduce_sum(s), rss = wave_reduce_sum(ss);
    int lane = t & 63, w = t >> 6;
    if (lane == 0) { red[w] = rs; red[8 + w] = rss; }
    __syncthreads();
    float mean = 0.f, msq = 0.f;
    #pragma unroll
    for (int i = 0; i < 4; ++i) { mean += red[i]; msq += red[8 + i]; }
    mean *= (1.0f / DD); msq *= (1.0f / DD);
    float rstd = rsqrtf(msq - mean * mean + 1e-5f);
    float2 gg = ((const float2*)g)[t], bb = ((const float2*)bta)[t];
    ushort2 o;
    o.x = f2bf((v.x - mean) * rstd * gg.x + bb.x);
    o.y = f2bf((v.y - mean) * rstd * gg.y + bb.y);
    ((ushort2*)(out + (size_t)row * DD))[t] = o;
}

extern "C" void kernel_launch(void* const* d_in, const int* in_sizes, int n_in,
                              void* d_out, int out_size, void* d_ws, size_t ws_size,
                              hipStream_t stream)
{
    const float* x          = (const float*)d_in[0];
    const int*   lengths    = (const int*)  d_in[1];
    const float* input_delay= (const float*)d_in[2];
    const float* c_local    = (const float*)d_in[3];
    const float* c_sink     = (const float*)d_in[4];
    const float* in_w       = (const float*)d_in[5];
    const float* in_b       = (const float*)d_in[6];
    const float* de_w1      = (const float*)d_in[7];
    const float* de_b1      = (const float*)d_in[8];
    const float* de_w2      = (const float*)d_in[9];
    const float* de_b2      = (const float*)d_in[10];
    const float* de_ln_g    = (const float*)d_in[11];
    const float* de_ln_b    = (const float*)d_in[12];
    const float* cpe_w      = (const float*)d_in[13];
    const float* cpe_b      = (const float*)d_in[14];
    const float* cpe_ln_g   = (const float*)d_in[15];
    const float* cpe_ln_b   = (const float*)d_in[16];
    const float* gain       = (const float*)d_in[17];
    const float* alpha      = (const float*)d_in[18];
    const float* beta       = (const float*)d_in[19];
    const float* floorp     = (const float*)d_in[20];
    const float* gammap     = (const float*)d_in[21];
    const float* inproj_w   = (const float*)d_in[22];
    const float* inproj_b   = (const float*)d_in[23];
    const float* outproj_w  = (const float*)d_in[24];
    const float* outproj_b  = (const float*)d_in[25];
    const float* ln1_g      = (const float*)d_in[26];
    const float* ln1_b      = (const float*)d_in[27];
    const float* ln2_g      = (const float*)d_in[28];
    const float* ln2_b      = (const float*)d_in[29];
    const float* ff_w1      = (const float*)d_in[30];
    const float* ff_b1      = (const float*)d_in[31];
    const float* ff_w2      = (const float*)d_in[32];
    const float* ff_b2      = (const float*)d_in[33];
    const float* out_ln_g   = (const float*)d_in[34];
    const float* out_ln_b   = (const float*)d_in[35];

    char* base = (char*)d_ws;
    float* h            = (float*)base;                               // 8 MB
    unsigned short* act1 = (unsigned short*)(base + 8u*1024*1024);    // 4 MB
    char* bigb          = base + 12u*1024*1024;                       // 16 MB shared region
    unsigned short* qkb  = (unsigned short*)bigb;                     // 8 MB (attn phase: Q,K)
    unsigned short* vtb  = (unsigned short*)(bigb + 12u*1024*1024);   // 4 MB (attn phase: V^T [512][4096])
    unsigned short* ffb  = (unsigned short*)bigb;                     // 16 MB (FF phase)
    unsigned short* Zb   = (unsigned short*)bigb;                     // 4.7 MB (embed phase)
    unsigned short* x_bf = (unsigned short*)(bigb + 5u*1024*1024);    // 0.5 MB
    float* cpe_pre       = (float*)(bigb + 8u*1024*1024);             // 8 MB
    unsigned short* w_inproj  = (unsigned short*)(base + 28u*1024*1024);
    unsigned short* w_outproj = w_inproj  + (size_t)3*1536*512;
    unsigned short* w_ff1     = w_outproj + (size_t)3*512*512;
    unsigned short* w_ff2     = w_ff1     + (size_t)3*2048*512;
    unsigned short* w_in      = w_ff2     + (size_t)3*512*2048;
    unsigned short* w_cpe     = w_in      + (size_t)512*64;
    float* e                  = (float*)(w_cpe + (size_t)512*FEATP);
    float* srow               = e + (size_t)BB*DD;

    // small prologue: PE/z (1024) | small converts (256) | delay (4)
    prologue_kernel<<<LL + 256 + BB, 256, 0, stream>>>(
        c_local, c_sink, lengths, beta, floorp, gammap, Zb, srow,
        x, in_w, cpe_w, x_bf, w_in, w_cpe,
        input_delay, de_w1, de_b1, de_w2, de_b2, de_ln_g, de_ln_b, e);

    // h0 GEMM + cpe GEMM + big-weight converts fused into one dispatch
    gemm_pre_dual<<<2048, 256, 0, stream>>>(x_bf, w_in, in_b, h, Zb, w_cpe, cpe_b, cpe_pre,
                                            inproj_w, outproj_w, ff_w1, ff_w2,
                                            w_inproj, w_outproj, w_ff1, w_ff2);
    embed_ep_kernel<<<MM, 256, 0, stream>>>(cpe_pre, e, lengths, cpe_ln_g, cpe_ln_b, gain, h);

    for (int i = 0; i < NLAYER; ++i) {
        const unsigned short* wqk = w_inproj + (size_t)i * 1536 * 512;          // Q,K rows [0,1024)
        const unsigned short* wv  = wqk + (size_t)1024 * 512;                   // V rows [1024,1536)
        ln_bf16_kernel<<<MM, 256, 0, stream>>>(h, act1, ln1_g + (size_t)i * DD, ln1_b + (size_t)i * DD);
        gemm_qkv_dual<<<1536, 256, 0, stream>>>(act1, wqk, inproj_b + (size_t)i * 1536,
                                                qkb, wv, inproj_b + (size_t)i * 1536 + 1024, vtb);
        attn_mfma<<<512, 256, 0, stream>>>(qkb, vtb, c_local, srow, lengths, alpha, act1);
        gemm_t<64, 64, 2, 2, 2, 2><<<dim3(DD / 64, MM / 64), 256, 0, stream>>>(
            act1, w_outproj + (size_t)i * 512 * 512, outproj_b + (size_t)i * DD,
            h, h, nullptr, MM, DD, DD);
        ln_bf16_kernel<<<MM, 256, 0, stream>>>(h, act1, ln2_g + (size_t)i * DD, ln2_b + (size_t)i * DD);
        gemm_t<128, 128, 4, 4, 2, 3><<<dim3(DFF / 128, MM / 128), 256, 0, stream>>>(
            act1, w_ff1 + (size_t)i * 2048 * 512, ff_b1 + (size_t)i * DFF,
            nullptr, nullptr, ffb, MM, DFF, DD);
        gemm_t<64, 64, 2, 2, 2, 2><<<dim3(DD / 64, MM / 64), 256, 0, stream>>>(
            ffb, w_ff2 + (size_t)i * 512 * 2048, ff_b2 + (size_t)i * DD,
            h, h, nullptr, MM, DD, DFF);
    }
    ln_kernel<<<MM, 256, 0, stream>>>(h, (float*)d_out, out_ln_g, out_ln_b);
}

// Round 22
// 394.887 us; speedup vs baseline: 1.0780x; 1.0780x over previous
//
#include <hip/hip_runtime.h>
#include <math.h>

#define BB 4
#define LL 1024
#define DIN 64
#define DD 512
#define HH 8
#define DH 64
#define NLAYER 3
#define DFF 2048
#define FEAT 530
#define FEATP 576
#define MM 4096

typedef float f32x4 __attribute__((ext_vector_type(4)));
typedef short s16x8 __attribute__((ext_vector_type(8)));

__device__ __forceinline__ unsigned short f2bf(float f) {
    unsigned int u = __float_as_uint(f);
    u += 0x7fffu + ((u >> 16) & 1u);
    return (unsigned short)(u >> 16);
}
__device__ __forceinline__ float bf2f(unsigned short u) {
    return __uint_as_float(((unsigned int)u) << 16);
}
__device__ __forceinline__ float gelu_exact(float x) {
    return 0.5f * x * (1.0f + erff(x * 0.7071067811865475f));
}
__device__ __forceinline__ float wave_reduce_sum(float v) {
    #pragma unroll
    for (int o = 32; o; o >>= 1) v += __shfl_down(v, o);
    return v;
}
__device__ __forceinline__ void gload16(const unsigned short* g, unsigned short* l) {
    __builtin_amdgcn_global_load_lds(
        (const __attribute__((address_space(1))) unsigned int*)g,
        (__attribute__((address_space(3))) unsigned int*)l, 16, 0, 0);
}
__device__ __forceinline__ void cvt16(const float* src, unsigned short* dst) {
    float4 f0 = ((const float4*)src)[0];
    float4 f1 = ((const float4*)src)[1];
    float4 f2 = ((const float4*)src)[2];
    float4 f3 = ((const float4*)src)[3];
    ushort4 o0, o1, o2, o3;
    o0.x = f2bf(f0.x); o0.y = f2bf(f0.y); o0.z = f2bf(f0.z); o0.w = f2bf(f0.w);
    o1.x = f2bf(f1.x); o1.y = f2bf(f1.y); o1.z = f2bf(f1.z); o1.w = f2bf(f1.w);
    o2.x = f2bf(f2.x); o2.y = f2bf(f2.y); o2.z = f2bf(f2.z); o2.w = f2bf(f2.w);
    o3.x = f2bf(f3.x); o3.y = f2bf(f3.y); o3.z = f2bf(f3.z); o3.w = f2bf(f3.w);
    ((ushort4*)dst)[0] = o0;
    ((ushort4*)dst)[1] = o1;
    ((ushort4*)dst)[2] = o2;
    ((ushort4*)dst)[3] = o3;
}

// ------------- small prologue: PE/z (1024) | small converts (256) | delay matvec (64) -------------
// delay: e_pre[b][d] = de_b2[d] + sum_j de_w2[d][j]*gelu(delay[b]*de_w1[j]+de_b1[j])
// spread across 16 blocks/batch (32 rows each) so the 1 MB de_w2 read is parallel
// across 64 CUs (one CU streaming it alone was a 44 us straggler: ~10 B/cyc/CU).
// The LN over e_pre moves into embed_ep (which already holds the full vector).
__global__ __launch_bounds__(256) void prologue_kernel(
    const float* __restrict__ c_local, const float* __restrict__ c_sink,
    const int* __restrict__ lengths,
    const float* __restrict__ beta_p, const float* __restrict__ floor_p,
    const float* __restrict__ gamma_p,
    unsigned short* __restrict__ Z, float* __restrict__ srow,
    const float* __restrict__ x, const float* __restrict__ in_w,
    const float* __restrict__ cpe_w,
    unsigned short* __restrict__ x_bf, unsigned short* __restrict__ w_in,
    unsigned short* __restrict__ w_cpe,
    const float* __restrict__ delay, const float* __restrict__ de_w1, const float* __restrict__ de_b1,
    const float* __restrict__ de_w2, const float* __restrict__ de_b2,
    float* __restrict__ e_pre)
{
    int blk = blockIdx.x;
    int t = threadIdx.x;

    if (blk < LL) {
        // ---- PE row l (shared by all 4 batches) + per-(b,l) tails ----
        int l = blk;
        for (int d = t; d < DD; d += 256) {
            int i = d >> 1;
            float dv = expf((float)(2 * i) * (-0.017988946135618352f)); // -ln(1e4)/512
            float ang = (float)l * dv;
            unsigned short pv = f2bf((d & 1) ? cosf(ang) : sinf(ang));
            #pragma unroll
            for (int bb = 0; bb < 4; ++bb)
                Z[(size_t)(bb * LL + l) * FEATP + d] = pv;
        }
        {
            int bb = t >> 6, j = t & 63;
            float cl = c_local[(size_t)bb * LL + l]; cl = fminf(fmaxf(cl, 0.f), 1.f);
            float cs = c_sink [(size_t)bb * LL + l]; cs = fminf(fmaxf(cs, 0.f), 1.f);
            float v = 0.f;
            if (j == 0) v = cl;
            else if (j == 1) v = cs;
            else if (j < 10)  { float c = (float)(j - 2) * (1.0f / 7.0f);  float df = (cl - c) / 0.200001f; v = expf(-0.5f * df * df); }
            else if (j < 18)  { float c = (float)(j - 10) * (1.0f / 7.0f); float df = (cs - c) / 0.200001f; v = expf(-0.5f * df * df); }
            Z[(size_t)(bb * LL + l) * FEATP + 512 + j] = (j < 18) ? f2bf(v) : 0;
            if (j == 32) {
                float sv = (*beta_p) * ((*floor_p) + (1.f - (*floor_p)) * powf(cs + 1e-6f, *gamma_p));
                srow[bb * LL + l] = (l < lengths[bb]) ? sv : 0.f;
            }
        }
    } else if (blk < LL + 256) {
        // ---- small converts: x, in_w, cpe pad ----
        const int N0s = MM * DIN;            // 262144
        const int N1s = N0s + 512 * 64;      // +32768
        const int NCHs = N1s / 16;
        int vb = blk - LL;
        for (int c = vb * 256 + t; c < NCHs; c += 256 * 256) {
            int i = c * 16;
            if (i < N0s) cvt16(x + i, x_bf + i);
            else         cvt16(in_w + (i - N0s), w_in + (i - N0s));
        }
        for (int j = vb * 256 + t; j < 512 * FEATP; j += 256 * 256) {
            int r = j / FEATP, c2 = j - r * FEATP;
            w_cpe[j] = (c2 < FEAT) ? f2bf(cpe_w[(size_t)r * FEAT + c2]) : 0;
        }
    } else {
        // ---- delay matvec: 64 blocks, 16 per batch, 32 rows per block ----
        __shared__ float g1[DD];
        int idx = blk - (LL + 256);          // 0..63
        int b  = idx >> 4;                   // batch
        int r0 = (idx & 15) * 32;            // first output row of this block
        float d0 = delay[b];
        g1[t]       = gelu_exact(d0 * de_w1[t]       + de_b1[t]);
        g1[t + 256] = gelu_exact(d0 * de_w1[t + 256] + de_b1[t + 256]);
        __syncthreads();
        int r = t >> 3, c = t & 7;           // 8 threads per row, 64-elem chunks
        const float* wr = de_w2 + (size_t)(r0 + r) * DD + c * 64;
        const float* gc = g1 + c * 64;
        float s = 0.f;
        #pragma unroll
        for (int j = 0; j < 64; j += 4) {
            float4 a4 = *(const float4*)(wr + j);
            s += a4.x * gc[j] + a4.y * gc[j+1] + a4.z * gc[j+2] + a4.w * gc[j+3];
        }
        s += __shfl_xor(s, 1);
        s += __shfl_xor(s, 2);
        s += __shfl_xor(s, 4);
        if (c == 0) e_pre[(size_t)b * DD + r0 + r] = s + de_b2[r0 + r];
    }
}

// ---- GEMM body (BK=64, dbuf LDS, runtime mode), shared by gemm_t and dual kernels ----
template<int BM, int BN, int FM, int FN, int WGN>
__device__ __forceinline__ void gemm_body(
    const unsigned short* __restrict__ A, const unsigned short* __restrict__ W,
    const float* __restrict__ bias, const float* __restrict__ resid,
    float* __restrict__ outf, unsigned short* __restrict__ outb,
    int M, int N, int K, int mode, int bm, int bn,
    unsigned short* As, unsigned short* Ws)
{
    int t = threadIdx.x;
    int lane = t & 63, wid = t >> 6;
    int wr = wid / WGN, wc = wid % WGN;
    int l15 = lane & 15, lg = lane >> 4;
    int sr = lane >> 3;
    int sc = ((lane & 7) ^ sr) * 8;
    int ph0 = (lg ^ (l15 & 7)) * 8;
    int ph1 = ((lg + 4) ^ (l15 & 7)) * 8;

    f32x4 acc[FM][FN] = {};
    int nk = K >> 6;

    auto stage = [&](int buf, int ks) {
        int kb = ks * 64;
        #pragma unroll
        for (int i = 0; i < BM / 32; ++i) {
            int row = wid * (BM / 4) + i * 8 + sr;
            gload16(A + (size_t)(bm + row) * K + kb + sc, &As[(size_t)buf * BM * 64 + (wid * (BM / 4) + i * 8) * 64]);
        }
        #pragma unroll
        for (int i = 0; i < BN / 32; ++i) {
            int row = wid * (BN / 4) + i * 8 + sr;
            gload16(W + (size_t)(bn + row) * K + kb + sc, &Ws[(size_t)buf * BN * 64 + (wid * (BN / 4) + i * 8) * 64]);
        }
    };

    stage(0, 0);
    __syncthreads();

    int cur = 0;
    for (int ks = 0; ks < nk; ++ks) {
        if (ks + 1 < nk) stage(cur ^ 1, ks + 1);
        s16x8 af0[FM], af1[FM], wf0[FN], wf1[FN];
        #pragma unroll
        for (int mi = 0; mi < FM; ++mi) {
            int row = wr * FM * 16 + mi * 16 + l15;
            af0[mi] = *(const s16x8*)&As[(size_t)cur * BM * 64 + row * 64 + ph0];
            af1[mi] = *(const s16x8*)&As[(size_t)cur * BM * 64 + row * 64 + ph1];
        }
        #pragma unroll
        for (int ni = 0; ni < FN; ++ni) {
            int row = wc * FN * 16 + ni * 16 + l15;
            wf0[ni] = *(const s16x8*)&Ws[(size_t)cur * BN * 64 + row * 64 + ph0];
            wf1[ni] = *(const s16x8*)&Ws[(size_t)cur * BN * 64 + row * 64 + ph1];
        }
        #pragma unroll
        for (int mi = 0; mi < FM; ++mi)
            #pragma unroll
            for (int ni = 0; ni < FN; ++ni) {
                acc[mi][ni] = __builtin_amdgcn_mfma_f32_16x16x32_bf16(af0[mi], wf0[ni], acc[mi][ni], 0, 0, 0);
                acc[mi][ni] = __builtin_amdgcn_mfma_f32_16x16x32_bf16(af1[mi], wf1[ni], acc[mi][ni], 0, 0, 0);
            }
        __syncthreads();
        cur ^= 1;
    }

    int rbase = (lane >> 4) * 4;
    #pragma unroll
    for (int mi = 0; mi < FM; ++mi) {
        #pragma unroll
        for (int ni = 0; ni < FN; ++ni) {
            int n = bn + wc * FN * 16 + ni * 16 + l15;
            float bzc = (mode == 4) ? 0.f : bias[n];
            #pragma unroll
            for (int r2 = 0; r2 < 4; ++r2) {
                int m = bm + wr * FM * 16 + mi * 16 + rbase + r2;
                float v = acc[mi][ni][r2] + ((mode == 4) ? bias[m] : bzc);
                size_t o = (size_t)m * N + n;
                if (mode == 0)      outf[o] = v;
                else if (mode == 1) outb[o] = f2bf(v);
                else if (mode == 2) outf[o] = v + resid[o];
                else if (mode == 3) outb[o] = f2bf(gelu_exact(v));
                else                outb[o] = f2bf(v);
            }
        }
    }
}

// ---- standalone templated GEMM ----
template<int BM, int BN, int FM, int FN, int WGN, int MODE>
__global__ __launch_bounds__(256) void gemm_t(
    const unsigned short* __restrict__ A, const unsigned short* __restrict__ W,
    const float* __restrict__ bias, const float* __restrict__ resid,
    float* __restrict__ outf, unsigned short* __restrict__ outb,
    int M, int N, int K)
{
    __shared__ __align__(16) unsigned short As[2 * BM * 64];
    __shared__ __align__(16) unsigned short Ws[2 * BN * 64];
    gemm_body<BM, BN, FM, FN, WGN>(A, W, bias, resid, outf, outb, M, N, K, MODE,
                                   blockIdx.y * BM, blockIdx.x * BN, As, Ws);
}

// ---- dual dispatch: h0 GEMM (512) + cpe GEMM (512) + big-weight converts (1024) ----
__global__ __launch_bounds__(256) void gemm_pre_dual(
    const unsigned short* __restrict__ x_bf, const unsigned short* __restrict__ w_in,
    const float* __restrict__ in_b, float* __restrict__ h,
    const unsigned short* __restrict__ Zb, const unsigned short* __restrict__ w_cpe,
    const float* __restrict__ cpe_b, float* __restrict__ cpe_pre,
    const float* __restrict__ inproj_w, const float* __restrict__ outproj_w,
    const float* __restrict__ ff_w1, const float* __restrict__ ff_w2,
    unsigned short* __restrict__ w_inproj, unsigned short* __restrict__ w_outproj,
    unsigned short* __restrict__ w_ff1, unsigned short* __restrict__ w_ff2)
{
    __shared__ __align__(16) unsigned short As[2 * 64 * 64];
    __shared__ __align__(16) unsigned short Ws[2 * 64 * 64];
    int id = blockIdx.x;
    if (id < 512) {
        gemm_body<64, 64, 2, 2, 2>(x_bf, w_in, in_b, nullptr, h, nullptr,
                                   MM, DD, DIN, 0, (id >> 3) * 64, (id & 7) * 64, As, Ws);
    } else if (id < 1024) {
        id -= 512;
        gemm_body<64, 64, 2, 2, 2>(Zb, w_cpe, cpe_b, nullptr, cpe_pre, nullptr,
                                   MM, DD, FEATP, 0, (id >> 3) * 64, (id & 7) * 64, As, Ws);
    } else {
        const int B0 = 3 * 1536 * 512;
        const int B1 = B0 + 3 * 512 * 512;
        const int B2 = B1 + 3 * 2048 * 512;
        const int B3 = B2 + 3 * 512 * 2048;
        const int NCH = B3 / 16;
        int vb = id - 1024;
        int t = threadIdx.x;
        for (int c = vb * 256 + t; c < NCH; c += 1024 * 256) {
            int i = c * 16;
            if (i < B0)      cvt16(inproj_w + i,         w_inproj + i);
            else if (i < B1) cvt16(outproj_w + (i - B0), w_outproj + (i - B0));
            else if (i < B2) cvt16(ff_w1 + (i - B1),     w_ff1 + (i - B1));
            else             cvt16(ff_w2 + (i - B2),     w_ff2 + (i - B2));
        }
    }
}

// ---- dual dispatch: QK GEMM (1024 blocks) + V^T GEMM (512 blocks) ----
__global__ __launch_bounds__(256) void gemm_qkv_dual(
    const unsigned short* __restrict__ act1,
    const unsigned short* __restrict__ wqk, const float* __restrict__ qk_bias,
    unsigned short* __restrict__ qkb,
    const unsigned short* __restrict__ wv, const float* __restrict__ v_bias,
    unsigned short* __restrict__ vtb)
{
    __shared__ __align__(16) unsigned short As[2 * 64 * 64];
    __shared__ __align__(16) unsigned short Ws[2 * 64 * 64];
    int id = blockIdx.x;
    if (id < 1024) {
        gemm_body<64, 64, 2, 2, 2>(act1, wqk, qk_bias, nullptr, nullptr, qkb,
                                   MM, 1024, DD, 1, (id >> 4) * 64, (id & 15) * 64, As, Ws);
    } else {
        id -= 1024;
        gemm_body<64, 64, 2, 2, 2>(wv, act1, v_bias, nullptr, nullptr, vtb,
                                   DD, MM, DD, 4, (id >> 6) * 64, (id & 63) * 64, As, Ws);
    }
}

// ------------- MFMA flash attention: natural block order (XCD-balanced), dbuf K/V -------------
#define SK 72
#define SPB 72
__global__ __launch_bounds__(256) void attn_mfma(
    const unsigned short* __restrict__ qk, const unsigned short* __restrict__ Vt,
    const float* __restrict__ c_local, const float* __restrict__ srow,
    const int* __restrict__ lengths,
    const float* __restrict__ alpha_p,
    unsigned short* __restrict__ o)
{
    __shared__ __align__(16) unsigned short Ks[2][64 * SK];
    __shared__ __align__(16) unsigned short Vts[2][64 * SK];
    __shared__ __align__(16) unsigned short Psb[64 * SPB];

    int id = blockIdx.x;
    int q0 = (id & 15) * 64;
    int hh = (id >> 4) & 7;
    int b  = id >> 7;

    int t  = threadIdx.x;
    int lane = t & 63, w = t >> 6;
    int l15 = lane & 15, lg = lane >> 4;
    int len = lengths[b];
    int nt = (len + 63) >> 6;
    int kt0 = q0 >> 6;
    bool sink_blk = (q0 == 0);
    const float alpha = *alpha_p;

    const unsigned short* qrow = qk + (size_t)(b * LL + q0 + w * 16 + l15) * 1024 + hh * DH;
    s16x8 qf0 = *(const s16x8*)(qrow + lg * 8);
    s16x8 qf1 = *(const s16x8*)(qrow + 32 + lg * 8);
    #pragma unroll
    for (int j = 0; j < 8; ++j) {
        qf0[j] = (short)f2bf(bf2f((unsigned short)qf0[j]) * 0.125f);
        qf1[j] = (short)f2bf(bf2f((unsigned short)qf1[j]) * 0.125f);
    }

    float cm1[4], cp1[4];
    #pragma unroll
    for (int r2 = 0; r2 < 4; ++r2) {
        int qi = q0 + w * 16 + lg * 4 + r2;
        cm1[r2] = 0.f; cp1[r2] = 0.f;
        if (qi >= 1 && qi < len) {
            int src = (qi == 1 || qi == LL - 1) ? qi : qi - 1;
            cm1[r2] = alpha * c_local[(size_t)b * LL + src];
        }
        if (qi + 1 < LL && qi < len)
            cp1[r2] = alpha * c_local[(size_t)b * LL + qi + 1];
    }
    bool need_sink = (sink_blk && w == 0 && lg == 0);

    float m_run[4], l_run[4];
    f32x4 accO[4] = {};
    #pragma unroll
    for (int r2 = 0; r2 < 4; ++r2) { m_run[r2] = -1e30f; l_run[r2] = 0.f; }

    int sr = t >> 3, sc8 = (t & 7) * 8;
    const unsigned short* kbase = qk + (size_t)(b * LL) * 1024 + 512 + hh * DH;
    const unsigned short* vbase = Vt + (size_t)(hh * DH) * MM + b * LL;

    uint4 pk0 = *(const uint4*)(kbase + (size_t)sr * 1024 + sc8);
    uint4 pk1 = *(const uint4*)(kbase + (size_t)(sr + 32) * 1024 + sc8);
    uint4 pv0 = *(const uint4*)(vbase + (size_t)sr * MM + sc8);
    uint4 pv1 = *(const uint4*)(vbase + (size_t)(sr + 32) * MM + sc8);
    *(uint4*)&Ks[0][sr * SK + sc8]         = pk0;
    *(uint4*)&Ks[0][(sr + 32) * SK + sc8]  = pk1;
    *(uint4*)&Vts[0][sr * SK + sc8]        = pv0;
    *(uint4*)&Vts[0][(sr + 32) * SK + sc8] = pv1;
    __syncthreads();

    int cur = 0;
    for (int kt = 0; kt < nt; ++kt) {
        int k0 = kt * 64;
        bool pre = (kt + 1 < nt);
        if (pre) {
            int kn = k0 + 64;
            pk0 = *(const uint4*)(kbase + (size_t)(kn + sr) * 1024 + sc8);
            pk1 = *(const uint4*)(kbase + (size_t)(kn + sr + 32) * 1024 + sc8);
            pv0 = *(const uint4*)(vbase + (size_t)sr * MM + kn + sc8);
            pv1 = *(const uint4*)(vbase + (size_t)(sr + 32) * MM + kn + sc8);
        }

        f32x4 accS[4] = {};
        #pragma unroll
        for (int ct = 0; ct < 4; ++ct) {
            s16x8 kf0 = *(const s16x8*)&Ks[cur][(ct * 16 + l15) * SK + lg * 8];
            s16x8 kf1 = *(const s16x8*)&Ks[cur][(ct * 16 + l15) * SK + 32 + lg * 8];
            accS[ct] = __builtin_amdgcn_mfma_f32_16x16x32_bf16(qf0, kf0, accS[ct], 0, 0, 0);
            accS[ct] = __builtin_amdgcn_mfma_f32_16x16x32_bf16(qf1, kf1, accS[ct], 0, 0, 0);
        }

        float m4[4] = { -1e30f, -1e30f, -1e30f, -1e30f };
        bool slow = sink_blk || (kt >= kt0 - 1 && kt <= kt0 + 1) || (k0 + 64 > len);
        if (!slow) {
            #pragma unroll
            for (int ct = 0; ct < 4; ++ct)
                #pragma unroll
                for (int r2 = 0; r2 < 4; ++r2)
                    m4[r2] = fmaxf(m4[r2], accS[ct][r2]);
        } else if (k0 + 64 <= len) {
            #pragma unroll
            for (int ct = 0; ct < 4; ++ct) {
                int k = k0 + ct * 16 + l15;
                float sink_ct = need_sink ? srow[(size_t)b * LL + k] : 0.f;
                #pragma unroll
                for (int r2 = 0; r2 < 4; ++r2) {
                    int qi = q0 + w * 16 + lg * 4 + r2;
                    float v = accS[ct][r2];
                    if (k == qi - 1) v += cm1[r2];
                    else if (k == qi + 1) v += cp1[r2];
                    if (r2 == 0) v += sink_ct;
                    accS[ct][r2] = v;
                    m4[r2] = fmaxf(m4[r2], v);
                }
            }
        } else {
            #pragma unroll
            for (int ct = 0; ct < 4; ++ct) {
                int k = k0 + ct * 16 + l15;
                bool maskk = (k >= len);
                float sink_ct = need_sink ? srow[(size_t)b * LL + k] : 0.f;
                #pragma unroll
                for (int r2 = 0; r2 < 4; ++r2) {
                    int qi = q0 + w * 16 + lg * 4 + r2;
                    float v = accS[ct][r2];
                    if (k == qi - 1) v += cm1[r2];
                    else if (k == qi + 1 && !maskk) v += cp1[r2];
                    if (r2 == 0) v += sink_ct;
                    if (maskk) v -= 10000.f;
                    accS[ct][r2] = v;
                    m4[r2] = fmaxf(m4[r2], v);
                }
            }
        }

        #pragma unroll
        for (int r2 = 0; r2 < 4; ++r2) {
            #pragma unroll
            for (int msk = 1; msk < 16; msk <<= 1) m4[r2] = fmaxf(m4[r2], __shfl_xor(m4[r2], msk));
            float mnew = fmaxf(m_run[r2], m4[r2]);
            float scl = __expf(m_run[r2] - mnew);
            m_run[r2] = mnew;
            float rowsum = 0.f;
            #pragma unroll
            for (int ct = 0; ct < 4; ++ct) {
                float p = __expf(accS[ct][r2] - mnew);
                rowsum += p;
                Psb[(w * 16 + lg * 4 + r2) * SPB + ct * 16 + l15] = f2bf(p);
            }
            #pragma unroll
            for (int msk = 1; msk < 16; msk <<= 1) rowsum += __shfl_xor(rowsum, msk);
            l_run[r2] = l_run[r2] * scl + rowsum;
            #pragma unroll
            for (int dt = 0; dt < 4; ++dt) accO[dt][r2] *= scl;
        }

        #pragma unroll
        for (int kk = 0; kk < 2; ++kk) {
            s16x8 pf = *(const s16x8*)&Psb[(w * 16 + l15) * SPB + kk * 32 + lg * 8];
            #pragma unroll
            for (int dt = 0; dt < 4; ++dt) {
                s16x8 vf = *(const s16x8*)&Vts[cur][(dt * 16 + l15) * SK + kk * 32 + lg * 8];
                accO[dt] = __builtin_amdgcn_mfma_f32_16x16x32_bf16(pf, vf, accO[dt], 0, 0, 0);
            }
        }

        if (pre) {
            int nxt = cur ^ 1;
            *(uint4*)&Ks[nxt][sr * SK + sc8]         = pk0;
            *(uint4*)&Ks[nxt][(sr + 32) * SK + sc8]  = pk1;
            *(uint4*)&Vts[nxt][sr * SK + sc8]        = pv0;
            *(uint4*)&Vts[nxt][(sr + 32) * SK + sc8] = pv1;
        }
        __syncthreads();
        cur ^= 1;
    }

    #pragma unroll
    for (int r2 = 0; r2 < 4; ++r2) {
        float inv = 1.f / l_run[r2];
        int qi = q0 + w * 16 + lg * 4 + r2;
        #pragma unroll
        for (int dt = 0; dt < 4; ++dt)
            o[(size_t)(b * LL + qi) * DD + hh * DH + dt * 16 + l15] = f2bf(accO[dt][r2] * inv);
    }
}

// ------ embed epilogue: h += LN(e_pre) + mask?0:gain*LN(cpe_pre) ------
__global__ __launch_bounds__(256) void embed_ep_kernel(
    const float* __restrict__ cpe_pre, const float* __restrict__ e_pre,
    const int* __restrict__ lengths,
    const float* __restrict__ cpe_g, const float* __restrict__ cpe_lb,
    const float* __restrict__ de_lng, const float* __restrict__ de_lnb,
    const float* __restrict__ gain_p, float* __restrict__ h)
{
    int row = blockIdx.x;
    int b = row >> 10, l = row & 1023;
    int t = threadIdx.x;
    __shared__ float red[32];
    const float* cp = cpe_pre + (size_t)row * DD;
    float v0 = cp[t], v1 = cp[t + 256];
    float e0 = e_pre[(size_t)b * DD + t], e1 = e_pre[(size_t)b * DD + t + 256];
    float s  = v0 + v1, ss  = v0 * v0 + v1 * v1;
    float s2 = e0 + e1, ss2 = e0 * e0 + e1 * e1;
    float rs  = wave_reduce_sum(s),  rss  = wave_reduce_sum(ss);
    float rs2 = wave_reduce_sum(s2), rss2 = wave_reduce_sum(ss2);
    int lane = t & 63, w = t >> 6;
    if (lane == 0) { red[w] = rs; red[8 + w] = rss; red[16 + w] = rs2; red[24 + w] = rss2; }
    __syncthreads();
    float mean = 0.f, msq = 0.f, mean_e = 0.f, msq_e = 0.f;
    #pragma unroll
    for (int i = 0; i < 4; ++i) {
        mean += red[i]; msq += red[8 + i];
        mean_e += red[16 + i]; msq_e += red[24 + i];
    }
    mean *= (1.0f / DD); msq *= (1.0f / DD);
    mean_e *= (1.0f / DD); msq_e *= (1.0f / DD);
    float rstd   = rsqrtf(msq - mean * mean + 1e-5f);
    float rstd_e = rsqrtf(msq_e - mean_e * mean_e + 1e-5f);
    float eln0 = (e0 - mean_e) * rstd_e * de_lng[t]       + de_lnb[t];
    float eln1 = (e1 - mean_e) * rstd_e * de_lng[t + 256] + de_lnb[t + 256];
    bool maskp = (l >= lengths[b]);
    float gain = *gain_p;
    float pe0 = maskp ? 0.f : gain * ((v0 - mean) * rstd * cpe_g[t] + cpe_lb[t]);
    float pe1 = maskp ? 0.f : gain * ((v1 - mean) * rstd * cpe_g[t + 256] + cpe_lb[t + 256]);
    h[(size_t)row * DD + t]       += eln0 + pe0;
    h[(size_t)row * DD + t + 256] += eln1 + pe1;
}

// ---------------- LayerNorm f32 out (final) ----------------
__global__ __launch_bounds__(256) void ln_kernel(
    const float* __restrict__ in, float* __restrict__ out,
    const float* __restrict__ g, const float* __restrict__ bta)
{
    int row = blockIdx.x; int t = threadIdx.x;
    __shared__ float red[16];
    const float* xr = in + (size_t)row * DD;
    float2 v = ((const float2*)xr)[t];
    float s = v.x + v.y, ss = v.x * v.x + v.y * v.y;
    float rs = wave_reduce_sum(s), rss = wave_reduce_sum(ss);
    int lane = t & 63, w = t >> 6;
    if (lane == 0) { red[w] = rs; red[8 + w] = rss; }
    __syncthreads();
    float mean = 0.f, msq = 0.f;
    #pragma unroll
    for (int i = 0; i < 4; ++i) { mean += red[i]; msq += red[8 + i]; }
    mean *= (1.0f / DD); msq *= (1.0f / DD);
    float rstd = rsqrtf(msq - mean * mean + 1e-5f);
    float2 gg = ((const float2*)g)[t], bb = ((const float2*)bta)[t];
    float2 o;
    o.x = (v.x - mean) * rstd * gg.x + bb.x;
    o.y = (v.y - mean) * rstd * gg.y + bb.y;
    ((float2*)(out + (size_t)row * DD))[t] = o;
}

// ---------------- LayerNorm bf16 out ----------------
__global__ __launch_bounds__(256) void ln_bf16_kernel(
    const float* __restrict__ in, unsigned short* __restrict__ out,
    const float* __restrict__ g, const float* __restrict__ bta)
{
    int row = blockIdx.x; int t = threadIdx.x;
    __shared__ float red[16];
    const float* xr = in + (size_t)row * DD;
    float2 v = ((const float2*)xr)[t];
    float s = v.x + v.y, ss = v.x * v.x + v.y * v.y;
    float rs = wave_reduce_sum(s), rss = wave_reduce_sum(ss);
    int lane = t & 63, w = t >> 6;
    if (lane == 0) { red[w] = rs; red[8 + w] = rss; }
    __syncthreads();
    float mean = 0.f, msq = 0.f;
    #pragma unroll
    for (int i = 0; i < 4; ++i) { mean += red[i]; msq += red[8 + i]; }
    mean *= (1.0f / DD); msq *= (1.0f / DD);
    float rstd = rsqrtf(msq - mean * mean + 1e-5f);
    float2 gg = ((const float2*)g)[t], bb = ((const float2*)bta)[t];
    ushort2 o;
    o.x = f2bf((v.x - mean) * rstd * gg.x + bb.x);
    o.y = f2bf((v.y - mean) * rstd * gg.y + bb.y);
    ((ushort2*)(out + (size_t)row * DD))[t] = o;
}

extern "C" void kernel_launch(void* const* d_in, const int* in_sizes, int n_in,
                              void* d_out, int out_size, void* d_ws, size_t ws_size,
                              hipStream_t stream)
{
    const float* x          = (const float*)d_in[0];
    const int*   lengths    = (const int*)  d_in[1];
    const float* input_delay= (const float*)d_in[2];
    const float* c_local    = (const float*)d_in[3];
    const float* c_sink     = (const float*)d_in[4];
    const float* in_w       = (const float*)d_in[5];
    const float* in_b       = (const float*)d_in[6];
    const float* de_w1      = (const float*)d_in[7];
    const float* de_b1      = (const float*)d_in[8];
    const float* de_w2      = (const float*)d_in[9];
    const float* de_b2      = (const float*)d_in[10];
    const float* de_ln_g    = (const float*)d_in[11];
    const float* de_ln_b    = (const float*)d_in[12];
    const float* cpe_w      = (const float*)d_in[13];
    const float* cpe_b      = (const float*)d_in[14];
    const float* cpe_ln_g   = (const float*)d_in[15];
    const float* cpe_ln_b   = (const float*)d_in[16];
    const float* gain       = (const float*)d_in[17];
    const float* alpha      = (const float*)d_in[18];
    const float* beta       = (const float*)d_in[19];
    const float* floorp     = (const float*)d_in[20];
    const float* gammap     = (const float*)d_in[21];
    const float* inproj_w   = (const float*)d_in[22];
    const float* inproj_b   = (const float*)d_in[23];
    const float* outproj_w  = (const float*)d_in[24];
    const float* outproj_b  = (const float*)d_in[25];
    const float* ln1_g      = (const float*)d_in[26];
    const float* ln1_b      = (const float*)d_in[27];
    const float* ln2_g      = (const float*)d_in[28];
    const float* ln2_b      = (const float*)d_in[29];
    const float* ff_w1      = (const float*)d_in[30];
    const float* ff_b1      = (const float*)d_in[31];
    const float* ff_w2      = (const float*)d_in[32];
    const float* ff_b2      = (const float*)d_in[33];
    const float* out_ln_g   = (const float*)d_in[34];
    const float* out_ln_b   = (const float*)d_in[35];

    char* base = (char*)d_ws;
    float* h            = (float*)base;                               // 8 MB
    unsigned short* act1 = (unsigned short*)(base + 8u*1024*1024);    // 4 MB
    char* bigb          = base + 12u*1024*1024;                       // 16 MB shared region
    unsigned short* qkb  = (unsigned short*)bigb;                     // 8 MB (attn phase: Q,K)
    unsigned short* vtb  = (unsigned short*)(bigb + 12u*1024*1024);   // 4 MB (attn phase: V^T [512][4096])
    unsigned short* ffb  = (unsigned short*)bigb;                     // 16 MB (FF phase)
    unsigned short* Zb   = (unsigned short*)bigb;                     // 4.7 MB (embed phase)
    unsigned short* x_bf = (unsigned short*)(bigb + 5u*1024*1024);    // 0.5 MB
    float* cpe_pre       = (float*)(bigb + 8u*1024*1024);             // 8 MB
    unsigned short* w_inproj  = (unsigned short*)(base + 28u*1024*1024);
    unsigned short* w_outproj = w_inproj  + (size_t)3*1536*512;
    unsigned short* w_ff1     = w_outproj + (size_t)3*512*512;
    unsigned short* w_ff2     = w_ff1     + (size_t)3*2048*512;
    unsigned short* w_in      = w_ff2     + (size_t)3*512*2048;
    unsigned short* w_cpe     = w_in      + (size_t)512*64;
    float* e_pre              = (float*)(w_cpe + (size_t)512*FEATP);
    float* srow               = e_pre + (size_t)BB*DD;

    // small prologue: PE/z (1024) | small converts (256) | delay matvec (64)
    prologue_kernel<<<LL + 256 + 64, 256, 0, stream>>>(
        c_local, c_sink, lengths, beta, floorp, gammap, Zb, srow,
        x, in_w, cpe_w, x_bf, w_in, w_cpe,
        input_delay, de_w1, de_b1, de_w2, de_b2, e_pre);

    // h0 GEMM + cpe GEMM + big-weight converts fused into one dispatch
    gemm_pre_dual<<<2048, 256, 0, stream>>>(x_bf, w_in, in_b, h, Zb, w_cpe, cpe_b, cpe_pre,
                                            inproj_w, outproj_w, ff_w1, ff_w2,
                                            w_inproj, w_outproj, w_ff1, w_ff2);
    embed_ep_kernel<<<MM, 256, 0, stream>>>(cpe_pre, e_pre, lengths, cpe_ln_g, cpe_ln_b,
                                            de_ln_g, de_ln_b, gain, h);

    for (int i = 0; i < NLAYER; ++i) {
        const unsigned short* wqk = w_inproj + (size_t)i * 1536 * 512;          // Q,K rows [0,1024)
        const unsigned short* wv  = wqk + (size_t)1024 * 512;                   // V rows [1024,1536)
        ln_bf16_kernel<<<MM, 256, 0, stream>>>(h, act1, ln1_g + (size_t)i * DD, ln1_b + (size_t)i * DD);
        gemm_qkv_dual<<<1536, 256, 0, stream>>>(act1, wqk, inproj_b + (size_t)i * 1536,
                                                qkb, wv, inproj_b + (size_t)i * 1536 + 1024, vtb);
        attn_mfma<<<512, 256, 0, stream>>>(qkb, vtb, c_local, srow, lengths, alpha, act1);
        gemm_t<64, 64, 2, 2, 2, 2><<<dim3(DD / 64, MM / 64), 256, 0, stream>>>(
            act1, w_outproj + (size_t)i * 512 * 512, outproj_b + (size_t)i * DD,
            h, h, nullptr, MM, DD, DD);
        ln_bf16_kernel<<<MM, 256, 0, stream>>>(h, act1, ln2_g + (size_t)i * DD, ln2_b + (size_t)i * DD);
        gemm_t<128, 128, 4, 4, 2, 3><<<dim3(DFF / 128, MM / 128), 256, 0, stream>>>(
            act1, w_ff1 + (size_t)i * 2048 * 512, ff_b1 + (size_t)i * DFF,
            nullptr, nullptr, ffb, MM, DFF, DD);
        gemm_t<64, 64, 2, 2, 2, 2><<<dim3(DD / 64, MM / 64), 256, 0, stream>>>(
            ffb, w_ff2 + (size_t)i * 512 * 2048, ff_b2 + (size_t)i * DD,
            h, h, nullptr, MM, DD, DFF);
    }
    ln_kernel<<<MM, 256, 0, stream>>>(h, (float*)d_out, out_ln_g, out_ln_b);
}

// Round 23
// 389.432 us; speedup vs baseline: 1.0931x; 1.0140x over previous
//
#include <hip/hip_runtime.h>
#include <math.h>

#define BB 4
#define LL 1024
#define DIN 64
#define DD 512
#define HH 8
#define DH 64
#define NLAYER 3
#define DFF 2048
#define FEAT 530
#define FEATP 576
#define MM 4096

typedef float f32x4 __attribute__((ext_vector_type(4)));
typedef short s16x8 __attribute__((ext_vector_type(8)));

__device__ __forceinline__ unsigned short f2bf(float f) {
    unsigned int u = __float_as_uint(f);
    u += 0x7fffu + ((u >> 16) & 1u);
    return (unsigned short)(u >> 16);
}
__device__ __forceinline__ float bf2f(unsigned short u) {
    return __uint_as_float(((unsigned int)u) << 16);
}
__device__ __forceinline__ float gelu_exact(float x) {
    return 0.5f * x * (1.0f + erff(x * 0.7071067811865475f));
}
__device__ __forceinline__ float wave_reduce_sum(float v) {
    #pragma unroll
    for (int o = 32; o; o >>= 1) v += __shfl_down(v, o);
    return v;
}
__device__ __forceinline__ void gload16(const unsigned short* g, unsigned short* l) {
    __builtin_amdgcn_global_load_lds(
        (const __attribute__((address_space(1))) unsigned int*)g,
        (__attribute__((address_space(3))) unsigned int*)l, 16, 0, 0);
}
__device__ __forceinline__ void cvt16(const float* src, unsigned short* dst) {
    float4 f0 = ((const float4*)src)[0];
    float4 f1 = ((const float4*)src)[1];
    float4 f2 = ((const float4*)src)[2];
    float4 f3 = ((const float4*)src)[3];
    ushort4 o0, o1, o2, o3;
    o0.x = f2bf(f0.x); o0.y = f2bf(f0.y); o0.z = f2bf(f0.z); o0.w = f2bf(f0.w);
    o1.x = f2bf(f1.x); o1.y = f2bf(f1.y); o1.z = f2bf(f1.z); o1.w = f2bf(f1.w);
    o2.x = f2bf(f2.x); o2.y = f2bf(f2.y); o2.z = f2bf(f2.z); o2.w = f2bf(f2.w);
    o3.x = f2bf(f3.x); o3.y = f2bf(f3.y); o3.z = f2bf(f3.z); o3.w = f2bf(f3.w);
    ((ushort4*)dst)[0] = o0;
    ((ushort4*)dst)[1] = o1;
    ((ushort4*)dst)[2] = o2;
    ((ushort4*)dst)[3] = o3;
}

// ------------- small prologue: PE/z (1024) | small converts (256) | delay matvec (64) -------------
__global__ __launch_bounds__(256) void prologue_kernel(
    const float* __restrict__ c_local, const float* __restrict__ c_sink,
    const int* __restrict__ lengths,
    const float* __restrict__ beta_p, const float* __restrict__ floor_p,
    const float* __restrict__ gamma_p,
    unsigned short* __restrict__ Z, float* __restrict__ srow,
    const float* __restrict__ x, const float* __restrict__ in_w,
    const float* __restrict__ cpe_w,
    unsigned short* __restrict__ x_bf, unsigned short* __restrict__ w_in,
    unsigned short* __restrict__ w_cpe,
    const float* __restrict__ delay, const float* __restrict__ de_w1, const float* __restrict__ de_b1,
    const float* __restrict__ de_w2, const float* __restrict__ de_b2,
    float* __restrict__ e_pre)
{
    int blk = blockIdx.x;
    int t = threadIdx.x;

    if (blk < LL) {
        int l = blk;
        for (int d = t; d < DD; d += 256) {
            int i = d >> 1;
            float dv = expf((float)(2 * i) * (-0.017988946135618352f)); // -ln(1e4)/512
            float ang = (float)l * dv;
            unsigned short pv = f2bf((d & 1) ? cosf(ang) : sinf(ang));
            #pragma unroll
            for (int bb = 0; bb < 4; ++bb)
                Z[(size_t)(bb * LL + l) * FEATP + d] = pv;
        }
        {
            int bb = t >> 6, j = t & 63;
            float cl = c_local[(size_t)bb * LL + l]; cl = fminf(fmaxf(cl, 0.f), 1.f);
            float cs = c_sink [(size_t)bb * LL + l]; cs = fminf(fmaxf(cs, 0.f), 1.f);
            float v = 0.f;
            if (j == 0) v = cl;
            else if (j == 1) v = cs;
            else if (j < 10)  { float c = (float)(j - 2) * (1.0f / 7.0f);  float df = (cl - c) / 0.200001f; v = expf(-0.5f * df * df); }
            else if (j < 18)  { float c = (float)(j - 10) * (1.0f / 7.0f); float df = (cs - c) / 0.200001f; v = expf(-0.5f * df * df); }
            Z[(size_t)(bb * LL + l) * FEATP + 512 + j] = (j < 18) ? f2bf(v) : 0;
            if (j == 32) {
                float sv = (*beta_p) * ((*floor_p) + (1.f - (*floor_p)) * powf(cs + 1e-6f, *gamma_p));
                srow[bb * LL + l] = (l < lengths[bb]) ? sv : 0.f;
            }
        }
    } else if (blk < LL + 256) {
        const int N0s = MM * DIN;
        const int N1s = N0s + 512 * 64;
        const int NCHs = N1s / 16;
        int vb = blk - LL;
        for (int c = vb * 256 + t; c < NCHs; c += 256 * 256) {
            int i = c * 16;
            if (i < N0s) cvt16(x + i, x_bf + i);
            else         cvt16(in_w + (i - N0s), w_in + (i - N0s));
        }
        for (int j = vb * 256 + t; j < 512 * FEATP; j += 256 * 256) {
            int r = j / FEATP, c2 = j - r * FEATP;
            w_cpe[j] = (c2 < FEAT) ? f2bf(cpe_w[(size_t)r * FEAT + c2]) : 0;
        }
    } else {
        __shared__ float g1[DD];
        int idx = blk - (LL + 256);
        int b  = idx >> 4;
        int r0 = (idx & 15) * 32;
        float d0 = delay[b];
        g1[t]       = gelu_exact(d0 * de_w1[t]       + de_b1[t]);
        g1[t + 256] = gelu_exact(d0 * de_w1[t + 256] + de_b1[t + 256]);
        __syncthreads();
        int r = t >> 3, c = t & 7;
        const float* wr = de_w2 + (size_t)(r0 + r) * DD + c * 64;
        const float* gc = g1 + c * 64;
        float s = 0.f;
        #pragma unroll
        for (int j = 0; j < 64; j += 4) {
            float4 a4 = *(const float4*)(wr + j);
            s += a4.x * gc[j] + a4.y * gc[j+1] + a4.z * gc[j+2] + a4.w * gc[j+3];
        }
        s += __shfl_xor(s, 1);
        s += __shfl_xor(s, 2);
        s += __shfl_xor(s, 4);
        if (c == 0) e_pre[(size_t)b * DD + r0 + r] = s + de_b2[r0 + r];
    }
}

// ---- GEMM body (BK=64, dbuf LDS, runtime mode) ----
// MODE 0: f32 out ; 1: bf16 out ; 2: bf16 out = acc+bias+bf16 resid ;
// 3: bf16 gelu ; 4: bf16 out, bias by ROW
template<int BM, int BN, int FM, int FN, int WGN>
__device__ __forceinline__ void gemm_body(
    const unsigned short* __restrict__ A, const unsigned short* __restrict__ W,
    const float* __restrict__ bias, const unsigned short* __restrict__ residb,
    float* __restrict__ outf, unsigned short* __restrict__ outb,
    int M, int N, int K, int mode, int bm, int bn,
    unsigned short* As, unsigned short* Ws)
{
    int t = threadIdx.x;
    int lane = t & 63, wid = t >> 6;
    int wr = wid / WGN, wc = wid % WGN;
    int l15 = lane & 15, lg = lane >> 4;
    int sr = lane >> 3;
    int sc = ((lane & 7) ^ sr) * 8;
    int ph0 = (lg ^ (l15 & 7)) * 8;
    int ph1 = ((lg + 4) ^ (l15 & 7)) * 8;

    f32x4 acc[FM][FN] = {};
    int nk = K >> 6;

    auto stage = [&](int buf, int ks) {
        int kb = ks * 64;
        #pragma unroll
        for (int i = 0; i < BM / 32; ++i) {
            int row = wid * (BM / 4) + i * 8 + sr;
            gload16(A + (size_t)(bm + row) * K + kb + sc, &As[(size_t)buf * BM * 64 + (wid * (BM / 4) + i * 8) * 64]);
        }
        #pragma unroll
        for (int i = 0; i < BN / 32; ++i) {
            int row = wid * (BN / 4) + i * 8 + sr;
            gload16(W + (size_t)(bn + row) * K + kb + sc, &Ws[(size_t)buf * BN * 64 + (wid * (BN / 4) + i * 8) * 64]);
        }
    };

    stage(0, 0);
    __syncthreads();

    int cur = 0;
    for (int ks = 0; ks < nk; ++ks) {
        if (ks + 1 < nk) stage(cur ^ 1, ks + 1);
        s16x8 af0[FM], af1[FM], wf0[FN], wf1[FN];
        #pragma unroll
        for (int mi = 0; mi < FM; ++mi) {
            int row = wr * FM * 16 + mi * 16 + l15;
            af0[mi] = *(const s16x8*)&As[(size_t)cur * BM * 64 + row * 64 + ph0];
            af1[mi] = *(const s16x8*)&As[(size_t)cur * BM * 64 + row * 64 + ph1];
        }
        #pragma unroll
        for (int ni = 0; ni < FN; ++ni) {
            int row = wc * FN * 16 + ni * 16 + l15;
            wf0[ni] = *(const s16x8*)&Ws[(size_t)cur * BN * 64 + row * 64 + ph0];
            wf1[ni] = *(const s16x8*)&Ws[(size_t)cur * BN * 64 + row * 64 + ph1];
        }
        #pragma unroll
        for (int mi = 0; mi < FM; ++mi)
            #pragma unroll
            for (int ni = 0; ni < FN; ++ni) {
                acc[mi][ni] = __builtin_amdgcn_mfma_f32_16x16x32_bf16(af0[mi], wf0[ni], acc[mi][ni], 0, 0, 0);
                acc[mi][ni] = __builtin_amdgcn_mfma_f32_16x16x32_bf16(af1[mi], wf1[ni], acc[mi][ni], 0, 0, 0);
            }
        __syncthreads();
        cur ^= 1;
    }

    int rbase = (lane >> 4) * 4;
    #pragma unroll
    for (int mi = 0; mi < FM; ++mi) {
        #pragma unroll
        for (int ni = 0; ni < FN; ++ni) {
            int n = bn + wc * FN * 16 + ni * 16 + l15;
            float bzc = (mode == 4) ? 0.f : bias[n];
            #pragma unroll
            for (int r2 = 0; r2 < 4; ++r2) {
                int m = bm + wr * FM * 16 + mi * 16 + rbase + r2;
                float v = acc[mi][ni][r2] + ((mode == 4) ? bias[m] : bzc);
                size_t o = (size_t)m * N + n;
                if (mode == 0)      outf[o] = v;
                else if (mode == 1) outb[o] = f2bf(v);
                else if (mode == 2) outb[o] = f2bf(v + bf2f(residb[o]));
                else if (mode == 3) outb[o] = f2bf(gelu_exact(v));
                else                outb[o] = f2bf(v);
            }
        }
    }
}

// ---- standalone templated GEMM ----
template<int BM, int BN, int FM, int FN, int WGN, int MODE>
__global__ __launch_bounds__(256) void gemm_t(
    const unsigned short* __restrict__ A, const unsigned short* __restrict__ W,
    const float* __restrict__ bias, const unsigned short* __restrict__ residb,
    float* __restrict__ outf, unsigned short* __restrict__ outb,
    int M, int N, int K)
{
    __shared__ __align__(16) unsigned short As[2 * BM * 64];
    __shared__ __align__(16) unsigned short Ws[2 * BN * 64];
    gemm_body<BM, BN, FM, FN, WGN>(A, W, bias, residb, outf, outb, M, N, K, MODE,
                                   blockIdx.y * BM, blockIdx.x * BN, As, Ws);
}

// ---- dual dispatch: h0 GEMM (512, bf16 out) + cpe GEMM (512) + big-weight converts (1024) ----
__global__ __launch_bounds__(256) void gemm_pre_dual(
    const unsigned short* __restrict__ x_bf, const unsigned short* __restrict__ w_in,
    const float* __restrict__ in_b, unsigned short* __restrict__ h,
    const unsigned short* __restrict__ Zb, const unsigned short* __restrict__ w_cpe,
    const float* __restrict__ cpe_b, float* __restrict__ cpe_pre,
    const float* __restrict__ inproj_w, const float* __restrict__ outproj_w,
    const float* __restrict__ ff_w1, const float* __restrict__ ff_w2,
    unsigned short* __restrict__ w_inproj, unsigned short* __restrict__ w_outproj,
    unsigned short* __restrict__ w_ff1, unsigned short* __restrict__ w_ff2)
{
    __shared__ __align__(16) unsigned short As[2 * 64 * 64];
    __shared__ __align__(16) unsigned short Ws[2 * 64 * 64];
    int id = blockIdx.x;
    if (id < 512) {
        gemm_body<64, 64, 2, 2, 2>(x_bf, w_in, in_b, nullptr, nullptr, h,
                                   MM, DD, DIN, 1, (id >> 3) * 64, (id & 7) * 64, As, Ws);
    } else if (id < 1024) {
        id -= 512;
        gemm_body<64, 64, 2, 2, 2>(Zb, w_cpe, cpe_b, nullptr, cpe_pre, nullptr,
                                   MM, DD, FEATP, 0, (id >> 3) * 64, (id & 7) * 64, As, Ws);
    } else {
        const int B0 = 3 * 1536 * 512;
        const int B1 = B0 + 3 * 512 * 512;
        const int B2 = B1 + 3 * 2048 * 512;
        const int B3 = B2 + 3 * 512 * 2048;
        const int NCH = B3 / 16;
        int vb = id - 1024;
        int t = threadIdx.x;
        for (int c = vb * 256 + t; c < NCH; c += 1024 * 256) {
            int i = c * 16;
            if (i < B0)      cvt16(inproj_w + i,         w_inproj + i);
            else if (i < B1) cvt16(outproj_w + (i - B0), w_outproj + (i - B0));
            else if (i < B2) cvt16(ff_w1 + (i - B1),     w_ff1 + (i - B1));
            else             cvt16(ff_w2 + (i - B2),     w_ff2 + (i - B2));
        }
    }
}

// ---- dual dispatch: QK GEMM (1024 blocks) + V^T GEMM (512 blocks) ----
__global__ __launch_bounds__(256) void gemm_qkv_dual(
    const unsigned short* __restrict__ act1,
    const unsigned short* __restrict__ wqk, const float* __restrict__ qk_bias,
    unsigned short* __restrict__ qkb,
    const unsigned short* __restrict__ wv, const float* __restrict__ v_bias,
    unsigned short* __restrict__ vtb)
{
    __shared__ __align__(16) unsigned short As[2 * 64 * 64];
    __shared__ __align__(16) unsigned short Ws[2 * 64 * 64];
    int id = blockIdx.x;
    if (id < 1024) {
        gemm_body<64, 64, 2, 2, 2>(act1, wqk, qk_bias, nullptr, nullptr, qkb,
                                   MM, 1024, DD, 1, (id >> 4) * 64, (id & 15) * 64, As, Ws);
    } else {
        id -= 1024;
        gemm_body<64, 64, 2, 2, 2>(wv, act1, v_bias, nullptr, nullptr, vtb,
                                   DD, MM, DD, 4, (id >> 6) * 64, (id & 63) * 64, As, Ws);
    }
}

// ------------- MFMA flash attention: natural block order (XCD-balanced), dbuf K/V -------------
#define SK 72
#define SPB 72
__global__ __launch_bounds__(256) void attn_mfma(
    const unsigned short* __restrict__ qk, const unsigned short* __restrict__ Vt,
    const float* __restrict__ c_local, const float* __restrict__ srow,
    const int* __restrict__ lengths,
    const float* __restrict__ alpha_p,
    unsigned short* __restrict__ o)
{
    __shared__ __align__(16) unsigned short Ks[2][64 * SK];
    __shared__ __align__(16) unsigned short Vts[2][64 * SK];
    __shared__ __align__(16) unsigned short Psb[64 * SPB];

    int id = blockIdx.x;
    int q0 = (id & 15) * 64;
    int hh = (id >> 4) & 7;
    int b  = id >> 7;

    int t  = threadIdx.x;
    int lane = t & 63, w = t >> 6;
    int l15 = lane & 15, lg = lane >> 4;
    int len = lengths[b];
    int nt = (len + 63) >> 6;
    int kt0 = q0 >> 6;
    bool sink_blk = (q0 == 0);
    const float alpha = *alpha_p;

    const unsigned short* qrow = qk + (size_t)(b * LL + q0 + w * 16 + l15) * 1024 + hh * DH;
    s16x8 qf0 = *(const s16x8*)(qrow + lg * 8);
    s16x8 qf1 = *(const s16x8*)(qrow + 32 + lg * 8);
    #pragma unroll
    for (int j = 0; j < 8; ++j) {
        qf0[j] = (short)f2bf(bf2f((unsigned short)qf0[j]) * 0.125f);
        qf1[j] = (short)f2bf(bf2f((unsigned short)qf1[j]) * 0.125f);
    }

    float cm1[4], cp1[4];
    #pragma unroll
    for (int r2 = 0; r2 < 4; ++r2) {
        int qi = q0 + w * 16 + lg * 4 + r2;
        cm1[r2] = 0.f; cp1[r2] = 0.f;
        if (qi >= 1 && qi < len) {
            int src = (qi == 1 || qi == LL - 1) ? qi : qi - 1;
            cm1[r2] = alpha * c_local[(size_t)b * LL + src];
        }
        if (qi + 1 < LL && qi < len)
            cp1[r2] = alpha * c_local[(size_t)b * LL + qi + 1];
    }
    bool need_sink = (sink_blk && w == 0 && lg == 0);

    float m_run[4], l_run[4];
    f32x4 accO[4] = {};
    #pragma unroll
    for (int r2 = 0; r2 < 4; ++r2) { m_run[r2] = -1e30f; l_run[r2] = 0.f; }

    int sr = t >> 3, sc8 = (t & 7) * 8;
    const unsigned short* kbase = qk + (size_t)(b * LL) * 1024 + 512 + hh * DH;
    const unsigned short* vbase = Vt + (size_t)(hh * DH) * MM + b * LL;

    uint4 pk0 = *(const uint4*)(kbase + (size_t)sr * 1024 + sc8);
    uint4 pk1 = *(const uint4*)(kbase + (size_t)(sr + 32) * 1024 + sc8);
    uint4 pv0 = *(const uint4*)(vbase + (size_t)sr * MM + sc8);
    uint4 pv1 = *(const uint4*)(vbase + (size_t)(sr + 32) * MM + sc8);
    *(uint4*)&Ks[0][sr * SK + sc8]         = pk0;
    *(uint4*)&Ks[0][(sr + 32) * SK + sc8]  = pk1;
    *(uint4*)&Vts[0][sr * SK + sc8]        = pv0;
    *(uint4*)&Vts[0][(sr + 32) * SK + sc8] = pv1;
    __syncthreads();

    int cur = 0;
    for (int kt = 0; kt < nt; ++kt) {
        int k0 = kt * 64;
        bool pre = (kt + 1 < nt);
        if (pre) {
            int kn = k0 + 64;
            pk0 = *(const uint4*)(kbase + (size_t)(kn + sr) * 1024 + sc8);
            pk1 = *(const uint4*)(kbase + (size_t)(kn + sr + 32) * 1024 + sc8);
            pv0 = *(const uint4*)(vbase + (size_t)sr * MM + kn + sc8);
            pv1 = *(const uint4*)(vbase + (size_t)(sr + 32) * MM + kn + sc8);
        }

        f32x4 accS[4] = {};
        #pragma unroll
        for (int ct = 0; ct < 4; ++ct) {
            s16x8 kf0 = *(const s16x8*)&Ks[cur][(ct * 16 + l15) * SK + lg * 8];
            s16x8 kf1 = *(const s16x8*)&Ks[cur][(ct * 16 + l15) * SK + 32 + lg * 8];
            accS[ct] = __builtin_amdgcn_mfma_f32_16x16x32_bf16(qf0, kf0, accS[ct], 0, 0, 0);
            accS[ct] = __builtin_amdgcn_mfma_f32_16x16x32_bf16(qf1, kf1, accS[ct], 0, 0, 0);
        }

        float m4[4] = { -1e30f, -1e30f, -1e30f, -1e30f };
        bool slow = sink_blk || (kt >= kt0 - 1 && kt <= kt0 + 1) || (k0 + 64 > len);
        if (!slow) {
            #pragma unroll
            for (int ct = 0; ct < 4; ++ct)
                #pragma unroll
                for (int r2 = 0; r2 < 4; ++r2)
                    m4[r2] = fmaxf(m4[r2], accS[ct][r2]);
        } else if (k0 + 64 <= len) {
            #pragma unroll
            for (int ct = 0; ct < 4; ++ct) {
                int k = k0 + ct * 16 + l15;
                float sink_ct = need_sink ? srow[(size_t)b * LL + k] : 0.f;
                #pragma unroll
                for (int r2 = 0; r2 < 4; ++r2) {
                    int qi = q0 + w * 16 + lg * 4 + r2;
                    float v = accS[ct][r2];
                    if (k == qi - 1) v += cm1[r2];
                    else if (k == qi + 1) v += cp1[r2];
                    if (r2 == 0) v += sink_ct;
                    accS[ct][r2] = v;
                    m4[r2] = fmaxf(m4[r2], v);
                }
            }
        } else {
            #pragma unroll
            for (int ct = 0; ct < 4; ++ct) {
                int k = k0 + ct * 16 + l15;
                bool maskk = (k >= len);
                float sink_ct = need_sink ? srow[(size_t)b * LL + k] : 0.f;
                #pragma unroll
                for (int r2 = 0; r2 < 4; ++r2) {
                    int qi = q0 + w * 16 + lg * 4 + r2;
                    float v = accS[ct][r2];
                    if (k == qi - 1) v += cm1[r2];
                    else if (k == qi + 1 && !maskk) v += cp1[r2];
                    if (r2 == 0) v += sink_ct;
                    if (maskk) v -= 10000.f;
                    accS[ct][r2] = v;
                    m4[r2] = fmaxf(m4[r2], v);
                }
            }
        }

        #pragma unroll
        for (int r2 = 0; r2 < 4; ++r2) {
            #pragma unroll
            for (int msk = 1; msk < 16; msk <<= 1) m4[r2] = fmaxf(m4[r2], __shfl_xor(m4[r2], msk));
            float mnew = fmaxf(m_run[r2], m4[r2]);
            float scl = __expf(m_run[r2] - mnew);
            m_run[r2] = mnew;
            float rowsum = 0.f;
            #pragma unroll
            for (int ct = 0; ct < 4; ++ct) {
                float p = __expf(accS[ct][r2] - mnew);
                rowsum += p;
                Psb[(w * 16 + lg * 4 + r2) * SPB + ct * 16 + l15] = f2bf(p);
            }
            #pragma unroll
            for (int msk = 1; msk < 16; msk <<= 1) rowsum += __shfl_xor(rowsum, msk);
            l_run[r2] = l_run[r2] * scl + rowsum;
            #pragma unroll
            for (int dt = 0; dt < 4; ++dt) accO[dt][r2] *= scl;
        }

        #pragma unroll
        for (int kk = 0; kk < 2; ++kk) {
            s16x8 pf = *(const s16x8*)&Psb[(w * 16 + l15) * SPB + kk * 32 + lg * 8];
            #pragma unroll
            for (int dt = 0; dt < 4; ++dt) {
                s16x8 vf = *(const s16x8*)&Vts[cur][(dt * 16 + l15) * SK + kk * 32 + lg * 8];
                accO[dt] = __builtin_amdgcn_mfma_f32_16x16x32_bf16(pf, vf, accO[dt], 0, 0, 0);
            }
        }

        if (pre) {
            int nxt = cur ^ 1;
            *(uint4*)&Ks[nxt][sr * SK + sc8]         = pk0;
            *(uint4*)&Ks[nxt][(sr + 32) * SK + sc8]  = pk1;
            *(uint4*)&Vts[nxt][sr * SK + sc8]        = pv0;
            *(uint4*)&Vts[nxt][(sr + 32) * SK + sc8] = pv1;
        }
        __syncthreads();
        cur ^= 1;
    }

    #pragma unroll
    for (int r2 = 0; r2 < 4; ++r2) {
        float inv = 1.f / l_run[r2];
        int qi = q0 + w * 16 + lg * 4 + r2;
        #pragma unroll
        for (int dt = 0; dt < 4; ++dt)
            o[(size_t)(b * LL + qi) * DD + hh * DH + dt * 16 + l15] = f2bf(accO[dt][r2] * inv);
    }
}

// ------ embed epilogue: h(bf16) += LN(e_pre) + mask?0:gain*LN(cpe_pre) ------
__global__ __launch_bounds__(256) void embed_ep_kernel(
    const float* __restrict__ cpe_pre, const float* __restrict__ e_pre,
    const int* __restrict__ lengths,
    const float* __restrict__ cpe_g, const float* __restrict__ cpe_lb,
    const float* __restrict__ de_lng, const float* __restrict__ de_lnb,
    const float* __restrict__ gain_p, unsigned short* __restrict__ h)
{
    int row = blockIdx.x;
    int b = row >> 10, l = row & 1023;
    int t = threadIdx.x;
    __shared__ float red[32];
    const float* cp = cpe_pre + (size_t)row * DD;
    float v0 = cp[t], v1 = cp[t + 256];
    float e0 = e_pre[(size_t)b * DD + t], e1 = e_pre[(size_t)b * DD + t + 256];
    float s  = v0 + v1, ss  = v0 * v0 + v1 * v1;
    float s2 = e0 + e1, ss2 = e0 * e0 + e1 * e1;
    float rs  = wave_reduce_sum(s),  rss  = wave_reduce_sum(ss);
    float rs2 = wave_reduce_sum(s2), rss2 = wave_reduce_sum(ss2);
    int lane = t & 63, w = t >> 6;
    if (lane == 0) { red[w] = rs; red[8 + w] = rss; red[16 + w] = rs2; red[24 + w] = rss2; }
    __syncthreads();
    float mean = 0.f, msq = 0.f, mean_e = 0.f, msq_e = 0.f;
    #pragma unroll
    for (int i = 0; i < 4; ++i) {
        mean += red[i]; msq += red[8 + i];
        mean_e += red[16 + i]; msq_e += red[24 + i];
    }
    mean *= (1.0f / DD); msq *= (1.0f / DD);
    mean_e *= (1.0f / DD); msq_e *= (1.0f / DD);
    float rstd   = rsqrtf(msq - mean * mean + 1e-5f);
    float rstd_e = rsqrtf(msq_e - mean_e * mean_e + 1e-5f);
    float eln0 = (e0 - mean_e) * rstd_e * de_lng[t]       + de_lnb[t];
    float eln1 = (e1 - mean_e) * rstd_e * de_lng[t + 256] + de_lnb[t + 256];
    bool maskp = (l >= lengths[b]);
    float gain = *gain_p;
    float pe0 = maskp ? 0.f : gain * ((v0 - mean) * rstd * cpe_g[t] + cpe_lb[t]);
    float pe1 = maskp ? 0.f : gain * ((v1 - mean) * rstd * cpe_g[t + 256] + cpe_lb[t + 256]);
    size_t o0 = (size_t)row * DD + t;
    size_t o1 = (size_t)row * DD + t + 256;
    h[o0] = f2bf(bf2f(h[o0]) + eln0 + pe0);
    h[o1] = f2bf(bf2f(h[o1]) + eln1 + pe1);
}

// ---------------- LayerNorm (bf16 in, f32 out — final) ----------------
__global__ __launch_bounds__(256) void ln_kernel(
    const unsigned short* __restrict__ in, float* __restrict__ out,
    const float* __restrict__ g, const float* __restrict__ bta)
{
    int row = blockIdx.x; int t = threadIdx.x;
    __shared__ float red[16];
    const unsigned short* xr = in + (size_t)row * DD;
    ushort2 u = ((const ushort2*)xr)[t];
    float vx = bf2f(u.x), vy = bf2f(u.y);
    float s = vx + vy, ss = vx * vx + vy * vy;
    float rs = wave_reduce_sum(s), rss = wave_reduce_sum(ss);
    int lane = t & 63, w = t >> 6;
    if (lane == 0) { red[w] = rs; red[8 + w] = rss; }
    __syncthreads();
    float mean = 0.f, msq = 0.f;
    #pragma unroll
    for (int i = 0; i < 4; ++i) { mean += red[i]; msq += red[8 + i]; }
    mean *= (1.0f / DD); msq *= (1.0f / DD);
    float rstd = rsqrtf(msq - mean * mean + 1e-5f);
    float2 gg = ((const float2*)g)[t], bb = ((const float2*)bta)[t];
    float2 o;
    o.x = (vx - mean) * rstd * gg.x + bb.x;
    o.y = (vy - mean) * rstd * gg.y + bb.y;
    ((float2*)(out + (size_t)row * DD))[t] = o;
}

// ---------------- LayerNorm (bf16 in, bf16 out) ----------------
__global__ __launch_bounds__(256) void ln_bf16_kernel(
    const unsigned short* __restrict__ in, unsigned short* __restrict__ out,
    const float* __restrict__ g, const float* __restrict__ bta)
{
    int row = blockIdx.x; int t = threadIdx.x;
    __shared__ float red[16];
    const unsigned short* xr = in + (size_t)row * DD;
    ushort2 u = ((const ushort2*)xr)[t];
    float vx = bf2f(u.x), vy = bf2f(u.y);
    float s = vx + vy, ss = vx * vx + vy * vy;
    float rs = wave_reduce_sum(s), rss = wave_reduce_sum(ss);
    int lane = t & 63, w = t >> 6;
    if (lane == 0) { red[w] = rs; red[8 + w] = rss; }
    __syncthreads();
    float mean = 0.f, msq = 0.f;
    #pragma unroll
    for (int i = 0; i < 4; ++i) { mean += red[i]; msq += red[8 + i]; }
    mean *= (1.0f / DD); msq *= (1.0f / DD);
    float rstd = rsqrtf(msq - mean * mean + 1e-5f);
    float2 gg = ((const float2*)g)[t], bb = ((const float2*)bta)[t];
    ushort2 o;
    o.x = f2bf((vx - mean) * rstd * gg.x + bb.x);
    o.y = f2bf((vy - mean) * rstd * gg.y + bb.y);
    ((ushort2*)(out + (size_t)row * DD))[t] = o;
}

extern "C" void kernel_launch(void* const* d_in, const int* in_sizes, int n_in,
                              void* d_out, int out_size, void* d_ws, size_t ws_size,
                              hipStream_t stream)
{
    const float* x          = (const float*)d_in[0];
    const int*   lengths    = (const int*)  d_in[1];
    const float* input_delay= (const float*)d_in[2];
    const float* c_local    = (const float*)d_in[3];
    const float* c_sink     = (const float*)d_in[4];
    const float* in_w       = (const float*)d_in[5];
    const float* in_b       = (const float*)d_in[6];
    const float* de_w1      = (const float*)d_in[7];
    const float* de_b1      = (const float*)d_in[8];
    const float* de_w2      = (const float*)d_in[9];
    const float* de_b2      = (const float*)d_in[10];
    const float* de_ln_g    = (const float*)d_in[11];
    const float* de_ln_b    = (const float*)d_in[12];
    const float* cpe_w      = (const float*)d_in[13];
    const float* cpe_b      = (const float*)d_in[14];
    const float* cpe_ln_g   = (const float*)d_in[15];
    const float* cpe_ln_b   = (const float*)d_in[16];
    const float* gain       = (const float*)d_in[17];
    const float* alpha      = (const float*)d_in[18];
    const float* beta       = (const float*)d_in[19];
    const float* floorp     = (const float*)d_in[20];
    const float* gammap     = (const float*)d_in[21];
    const float* inproj_w   = (const float*)d_in[22];
    const float* inproj_b   = (const float*)d_in[23];
    const float* outproj_w  = (const float*)d_in[24];
    const float* outproj_b  = (const float*)d_in[25];
    const float* ln1_g      = (const float*)d_in[26];
    const float* ln1_b      = (const float*)d_in[27];
    const float* ln2_g      = (const float*)d_in[28];
    const float* ln2_b      = (const float*)d_in[29];
    const float* ff_w1      = (const float*)d_in[30];
    const float* ff_b1      = (const float*)d_in[31];
    const float* ff_w2      = (const float*)d_in[32];
    const float* ff_b2      = (const float*)d_in[33];
    const float* out_ln_g   = (const float*)d_in[34];
    const float* out_ln_b   = (const float*)d_in[35];

    char* base = (char*)d_ws;
    unsigned short* h    = (unsigned short*)base;                     // 4 MB (bf16 residual)
    unsigned short* act1 = (unsigned short*)(base + 8u*1024*1024);    // 4 MB
    char* bigb          = base + 12u*1024*1024;                       // 16 MB shared region
    unsigned short* qkb  = (unsigned short*)bigb;                     // 8 MB (attn phase: Q,K)
    unsigned short* vtb  = (unsigned short*)(bigb + 12u*1024*1024);   // 4 MB (attn phase: V^T [512][4096])
    unsigned short* ffb  = (unsigned short*)bigb;                     // 16 MB (FF phase)
    unsigned short* Zb   = (unsigned short*)bigb;                     // 4.7 MB (embed phase)
    unsigned short* x_bf = (unsigned short*)(bigb + 5u*1024*1024);    // 0.5 MB
    float* cpe_pre       = (float*)(bigb + 8u*1024*1024);             // 8 MB
    unsigned short* w_inproj  = (unsigned short*)(base + 28u*1024*1024);
    unsigned short* w_outproj = w_inproj  + (size_t)3*1536*512;
    unsigned short* w_ff1     = w_outproj + (size_t)3*512*512;
    unsigned short* w_ff2     = w_ff1     + (size_t)3*2048*512;
    unsigned short* w_in      = w_ff2     + (size_t)3*512*2048;
    unsigned short* w_cpe     = w_in      + (size_t)512*64;
    float* e_pre              = (float*)(w_cpe + (size_t)512*FEATP);
    float* srow               = e_pre + (size_t)BB*DD;

    // small prologue: PE/z (1024) | small converts (256) | delay matvec (64)
    prologue_kernel<<<LL + 256 + 64, 256, 0, stream>>>(
        c_local, c_sink, lengths, beta, floorp, gammap, Zb, srow,
        x, in_w, cpe_w, x_bf, w_in, w_cpe,
        input_delay, de_w1, de_b1, de_w2, de_b2, e_pre);

    // h0 GEMM (bf16) + cpe GEMM + big-weight converts fused into one dispatch
    gemm_pre_dual<<<2048, 256, 0, stream>>>(x_bf, w_in, in_b, h, Zb, w_cpe, cpe_b, cpe_pre,
                                            inproj_w, outproj_w, ff_w1, ff_w2,
                                            w_inproj, w_outproj, w_ff1, w_ff2);
    embed_ep_kernel<<<MM, 256, 0, stream>>>(cpe_pre, e_pre, lengths, cpe_ln_g, cpe_ln_b,
                                            de_ln_g, de_ln_b, gain, h);

    for (int i = 0; i < NLAYER; ++i) {
        const unsigned short* wqk = w_inproj + (size_t)i * 1536 * 512;          // Q,K rows [0,1024)
        const unsigned short* wv  = wqk + (size_t)1024 * 512;                   // V rows [1024,1536)
        ln_bf16_kernel<<<MM, 256, 0, stream>>>(h, act1, ln1_g + (size_t)i * DD, ln1_b + (size_t)i * DD);
        gemm_qkv_dual<<<1536, 256, 0, stream>>>(act1, wqk, inproj_b + (size_t)i * 1536,
                                                qkb, wv, inproj_b + (size_t)i * 1536 + 1024, vtb);
        attn_mfma<<<512, 256, 0, stream>>>(qkb, vtb, c_local, srow, lengths, alpha, act1);
        gemm_t<64, 64, 2, 2, 2, 2><<<dim3(DD / 64, MM / 64), 256, 0, stream>>>(
            act1, w_outproj + (size_t)i * 512 * 512, outproj_b + (size_t)i * DD,
            h, nullptr, h, MM, DD, DD);
        ln_bf16_kernel<<<MM, 256, 0, stream>>>(h, act1, ln2_g + (size_t)i * DD, ln2_b + (size_t)i * DD);
        gemm_t<128, 128, 4, 4, 2, 3><<<dim3(DFF / 128, MM / 128), 256, 0, stream>>>(
            act1, w_ff1 + (size_t)i * 2048 * 512, ff_b1 + (size_t)i * DFF,
            nullptr, nullptr, ffb, MM, DFF, DD);
        gemm_t<64, 64, 2, 2, 2, 2><<<dim3(DD / 64, MM / 64), 256, 0, stream>>>(
            ffb, w_ff2 + (size_t)i * 512 * 2048, ff_b2 + (size_t)i * DD,
            h, nullptr, h, MM, DD, DFF);
    }
    ln_kernel<<<MM, 256, 0, stream>>>(h, (float*)d_out, out_ln_g, out_ln_b);
}